// Round 1
// baseline (308.316 us; speedup 1.0000x reference)
//
#include <hip/hip_runtime.h>
#include <hip/hip_bf16.h>

// ---------------- problem dims ----------------
// B=2, Cin=512, C=64, H=W=48, N=2304 spatial, 4608 total columns.

// ---------------- ws layout (float offsets) ----------------
static constexpr size_t OFF_P1 = 0;                       // [2][512] pooled ps=1 (col-major per col)
static constexpr size_t OFF_P3 = OFF_P1 + 2*512;          // [2*9][512]
static constexpr size_t OFF_P5 = OFF_P3 + 18*512;         // [2*25][512]
static constexpr size_t OFF_G0 = OFF_P5 + 50*512;         // [2*1][64]  relu(conv(pool))
static constexpr size_t OFF_G1 = OFF_G0 + 2*64;           // [2*9][64]
static constexpr size_t OFF_G2 = OFF_G1 + 18*64;          // [2*25][64]
static constexpr size_t OFF_S  = OFF_G2 + 50*64;          // [2][64][2304]
static constexpr size_t OFF_Q  = OFF_S  + 294912;         // [2][8][2304]
static constexpr size_t OFF_K  = OFF_Q  + 36864;          // [2][8][2304]
static constexpr size_t OFF_V  = OFF_K  + 36864;          // [2][64][2304]
static constexpr size_t OFF_SAP= OFF_V  + 294912;         // [4][2][64][2304] PV n-split partials
static constexpr size_t OFF_SA = OFF_SAP+ 4*294912;       // [2][64][2304]
static constexpr size_t OFF_GC = OFF_SA + 294912;         // [3][2][64][2304] upsampled gcs
static constexpr size_t OFF_MEAN = OFF_GC + 3*294912;     // [2][4][64]
static constexpr size_t OFF_WGT  = OFF_MEAN + 512;        // [2][4][64]
static constexpr size_t OFF_FUSED= OFF_WGT + 512;         // [2][256][2304]
static constexpr size_t OFF_Y0 = OFF_FUSED + 1179648;     // [2][256][2304]
static constexpr size_t OFF_Y1 = OFF_Y0 + 1179648;        // [2][128][2304]
static constexpr size_t OFF_Y2 = OFF_Y1 + 589824;         // [2][64][2304]
static constexpr size_t OFF_Y3 = OFF_Y2 + 294912;         // [2][64][2304]
static constexpr size_t OFF_PA = OFF_Y3 + 294912;         // bf16 [2][2304][2304] attn probs
// total ~11.9M floats = 47.7 MB

// ---------------- K1: adaptive pools (1,3,5) ----------------
__global__ __launch_bounds__(256) void k_pool(const float* __restrict__ x, float* __restrict__ wsp){
  __shared__ float pl[2304];
  __shared__ float red[4];
  int bc = blockIdx.x;            // b*512 + cin
  int b = bc >> 9, cin = bc & 511;
  const float* src = x + (size_t)bc * 2304;
  int t = threadIdx.x;
  float ls = 0.f;
  #pragma unroll
  for (int j = 0; j < 9; j++){ int i = t + j*256; float v = src[i]; pl[i] = v; ls += v; }
  #pragma unroll
  for (int o = 32; o; o >>= 1) ls += __shfl_xor(ls, o);
  if ((t & 63) == 0) red[t >> 6] = ls;
  __syncthreads();
  if (t == 0) wsp[OFF_P1 + (size_t)b*512 + cin] = (red[0]+red[1]+red[2]+red[3]) * (1.f/2304.f);
  if (t < 9){
    int ry = t/3, rx = t%3; float sm = 0.f;
    for (int yy = 0; yy < 16; yy++)
      for (int xx = 0; xx < 16; xx++) sm += pl[(ry*16+yy)*48 + rx*16+xx];
    wsp[OFF_P3 + ((size_t)b*9 + t)*512 + cin] = sm * (1.f/256.f);
  } else if (t < 34){
    int j = t - 9; int ry = j/5, rx = j%5;
    int hs = (ry*48)/5, he = ((ry+1)*48+4)/5, cs = (rx*48)/5, ce = ((rx+1)*48+4)/5;
    float sm = 0.f;
    for (int yy = hs; yy < he; yy++)
      for (int xx = cs; xx < ce; xx++) sm += pl[yy*48+xx];
    wsp[OFF_P5 + ((size_t)b*25 + j)*512 + cin] = sm / (float)((he-hs)*(ce-cs));
  }
}

// ---------------- K2: tiny 64x512 convs on pooled cols ----------------
__global__ __launch_bounds__(256) void k_gcconv(
    const float* __restrict__ w0, const float* __restrict__ b0,
    const float* __restrict__ w1, const float* __restrict__ b1,
    const float* __restrict__ w2, const float* __restrict__ b2,
    float* __restrict__ wsp){
  int col = blockIdx.x;          // 0..69 : 2 + 18 + 50
  const float* w; const float* bias; const float* pool; float* dst;
  if (col < 2){ w = w0; bias = b0; pool = wsp + OFF_P1 + (size_t)col*512; dst = wsp + OFF_G0 + (size_t)col*64; }
  else if (col < 20){ int c = col-2;  w = w1; bias = b1; pool = wsp + OFF_P3 + (size_t)c*512; dst = wsp + OFF_G1 + (size_t)c*64; }
  else              { int c = col-20; w = w2; bias = b2; pool = wsp + OFF_P5 + (size_t)c*512; dst = wsp + OFF_G2 + (size_t)c*64; }
  int t = threadIdx.x; int r = t >> 2, qd = t & 3;
  const float* wr = w + (size_t)r*512 + qd*128;
  const float* pr = pool + qd*128;
  float acc = 0.f;
  #pragma unroll 8
  for (int k = 0; k < 128; k += 4){
    float4 wv = *(const float4*)(wr + k); float4 pv = *(const float4*)(pr + k);
    acc += wv.x*pv.x + wv.y*pv.y + wv.z*pv.z + wv.w*pv.w;
  }
  acc += __shfl_xor(acc, 1); acc += __shfl_xor(acc, 2);
  if (qd == 0) dst[r] = fmaxf(acc + bias[r], 0.f);
}

// ---------------- K3: s = relu(Wgc3 . x + b)  M=64,K=512,N=4608 ----------------
__global__ __launch_bounds__(256) void k_sgemm(const float* __restrict__ x,
    const float* __restrict__ w, const float* __restrict__ bias, float* __restrict__ wsp){
  __shared__ __align__(16) float wt[64][68];   // [k][r] transposed chunk
  int cb = blockIdx.x;                          // 72: b*36 + coltile
  int b = cb / 36, hw0 = (cb - b*36)*64;
  int tid = threadIdx.x;
  int sr = tid >> 2, sseg = tid & 3;
  int cc0 = (tid & 15)*4, r0 = (tid >> 4)*4;
  const float* xb = x + (size_t)b*512*2304 + hw0 + cc0;
  float acc[4][4] = {};
  for (int kc = 0; kc < 512; kc += 64){
    __syncthreads();
    #pragma unroll
    for (int i = 0; i < 16; i += 4){
      float4 v = *(const float4*)(w + (size_t)sr*512 + kc + sseg*16 + i);
      wt[sseg*16+i+0][sr]=v.x; wt[sseg*16+i+1][sr]=v.y;
      wt[sseg*16+i+2][sr]=v.z; wt[sseg*16+i+3][sr]=v.w;
    }
    __syncthreads();
    const float* xk = xb + (size_t)kc*2304;
    #pragma unroll 4
    for (int k = 0; k < 64; k++){
      float4 wv = *(const float4*)&wt[k][r0];
      float4 xv = *(const float4*)(xk + (size_t)k*2304);
      acc[0][0]+=wv.x*xv.x; acc[0][1]+=wv.x*xv.y; acc[0][2]+=wv.x*xv.z; acc[0][3]+=wv.x*xv.w;
      acc[1][0]+=wv.y*xv.x; acc[1][1]+=wv.y*xv.y; acc[1][2]+=wv.y*xv.z; acc[1][3]+=wv.y*xv.w;
      acc[2][0]+=wv.z*xv.x; acc[2][1]+=wv.z*xv.y; acc[2][2]+=wv.z*xv.z; acc[2][3]+=wv.z*xv.w;
      acc[3][0]+=wv.w*xv.x; acc[3][1]+=wv.w*xv.y; acc[3][2]+=wv.w*xv.z; acc[3][3]+=wv.w*xv.w;
    }
  }
  #pragma unroll
  for (int i = 0; i < 4; i++){
    float bi = bias[r0+i];
    float4 o;
    o.x = fmaxf(acc[i][0]+bi, 0.f); o.y = fmaxf(acc[i][1]+bi, 0.f);
    o.z = fmaxf(acc[i][2]+bi, 0.f); o.w = fmaxf(acc[i][3]+bi, 0.f);
    *(float4*)(wsp + OFF_S + ((size_t)b*64 + r0+i)*2304 + hw0 + cc0) = o;
  }
}

// ---------------- K4: q,k,v projections (80 rows, K=64) ----------------
__global__ __launch_bounds__(256) void k_qkv(
    const float* __restrict__ wq, const float* __restrict__ bq,
    const float* __restrict__ wk, const float* __restrict__ bk,
    const float* __restrict__ wv, const float* __restrict__ bv,
    float* __restrict__ wsp){
  __shared__ float wl[16][64];
  __shared__ float bl[16];
  int tid = threadIdx.x;
  int rg = blockIdx.y;                   // 5 row groups of 16
  for (int i = tid; i < 1024; i += 256){
    int r = i >> 6, k = i & 63;
    int gr = rg*16 + r;
    const float* w = (gr < 8) ? (wq + (size_t)gr*64) : (gr < 16 ? wk + (size_t)(gr-8)*64 : wv + (size_t)(gr-16)*64);
    wl[r][k] = w[k];
  }
  if (tid < 16){
    int gr = rg*16 + tid;
    bl[tid] = (gr < 8) ? bq[gr] : (gr < 16 ? bk[gr-8] : bv[gr-16]);
  }
  __syncthreads();
  int col = blockIdx.x*256 + tid;        // 0..4607
  int b = col / 2304; int hw = col - b*2304;
  const float* sp = wsp + OFF_S + (size_t)b*147456 + hw;
  float acc[16];
  #pragma unroll
  for (int r = 0; r < 16; r++) acc[r] = bl[r];
  for (int k = 0; k < 64; k++){
    float sv = sp[(size_t)k*2304];
    #pragma unroll
    for (int r = 0; r < 16; r++) acc[r] += wl[r][k]*sv;
  }
  #pragma unroll
  for (int r = 0; r < 16; r++){
    int gr = rg*16 + r;
    float* dst;
    if (gr < 8)       dst = wsp + OFF_Q + (size_t)b*18432 + (size_t)gr*2304;
    else if (gr < 16) dst = wsp + OFF_K + (size_t)b*18432 + (size_t)(gr-8)*2304;
    else              dst = wsp + OFF_V + (size_t)b*147456 + (size_t)(gr-16)*2304;
    dst[hw] = acc[r];
  }
}

// ---------------- K5: attention logits + softmax -> P (bf16) ----------------
__global__ __launch_bounds__(256) void k_softmax(float* __restrict__ wsp){
  int blk = blockIdx.x; int b = blk / 2304; int m = blk - b*2304;
  const float* q  = wsp + OFF_Q + (size_t)b*18432 + m;
  const float* kk = wsp + OFF_K + (size_t)b*18432;
  __hip_bfloat16* P = reinterpret_cast<__hip_bfloat16*>(wsp + OFF_PA) + (size_t)(b*2304 + m)*2304;
  float qv[8];
  #pragma unroll
  for (int c = 0; c < 8; c++) qv[c] = q[(size_t)c*2304];
  int t = threadIdx.x;
  float l[9];
  float lmax = -1e30f;
  #pragma unroll
  for (int j = 0; j < 9; j++){
    int n = t + j*256;
    float acc = 0.f;
    #pragma unroll
    for (int c = 0; c < 8; c++) acc += qv[c]*kk[(size_t)c*2304 + n];
    l[j] = acc; lmax = fmaxf(lmax, acc);
  }
  __shared__ float rmax[4], rsum[4];
  #pragma unroll
  for (int o = 32; o; o >>= 1) lmax = fmaxf(lmax, __shfl_xor(lmax, o));
  if ((t & 63) == 0) rmax[t >> 6] = lmax;
  __syncthreads();
  float M = fmaxf(fmaxf(rmax[0], rmax[1]), fmaxf(rmax[2], rmax[3]));
  float s = 0.f;
  #pragma unroll
  for (int j = 0; j < 9; j++){ l[j] = __expf(l[j]-M); s += l[j]; }
  #pragma unroll
  for (int o = 32; o; o >>= 1) s += __shfl_xor(s, o);
  if ((t & 63) == 0) rsum[t >> 6] = s;
  __syncthreads();
  float inv = 1.f / (rsum[0]+rsum[1]+rsum[2]+rsum[3]);
  #pragma unroll
  for (int j = 0; j < 9; j++){
    int n = t + j*256;
    P[n] = __float2bfloat16(l[j]*inv);
  }
}

// ---------------- K6: sa_partial = P . V^T  (n-split 4) ----------------
__global__ __launch_bounds__(256) void k_pv(float* __restrict__ wsp){
  __shared__ __align__(16) float pt[64][68];  // [n][m]
  __shared__ __align__(16) float vt[64][68];  // [n][c]
  int mbase = blockIdx.x * 64;   // 36 tiles
  int b  = blockIdx.y;           // 2
  int ns = blockIdx.z;           // 4
  const __hip_bfloat16* P = reinterpret_cast<const __hip_bfloat16*>(wsp + OFF_PA) + (size_t)b*2304*2304;
  const float* V = wsp + OFF_V + (size_t)b*147456;
  int tid = threadIdx.x;
  int mg = tid & 15, cg = tid >> 4;       // m0 = mg*4 (lane-fast for coalesced store), c0 = cg*4
  int sr = tid >> 2, sseg = tid & 3;
  float acc[4][4] = {};                   // [ci][mi]
  for (int ch = 0; ch < 9; ch++){
    int nb = ns*576 + ch*64;
    {
      const unsigned short* s16 = (const unsigned short*)(P + (size_t)(mbase+sr)*2304 + nb + sseg*16);
      #pragma unroll
      for (int i = 0; i < 16; i++) pt[sseg*16+i][sr] = __uint_as_float(((unsigned)s16[i]) << 16);
    }
    {
      const float* vs = V + (size_t)sr*2304 + nb + sseg*16;
      #pragma unroll
      for (int i = 0; i < 16; i++) vt[sseg*16+i][sr] = vs[i];
    }
    __syncthreads();
    #pragma unroll 4
    for (int n = 0; n < 64; n++){
      float4 p4 = *(const float4*)&pt[n][mg*4];
      float4 v4 = *(const float4*)&vt[n][cg*4];
      acc[0][0]+=v4.x*p4.x; acc[0][1]+=v4.x*p4.y; acc[0][2]+=v4.x*p4.z; acc[0][3]+=v4.x*p4.w;
      acc[1][0]+=v4.y*p4.x; acc[1][1]+=v4.y*p4.y; acc[1][2]+=v4.y*p4.z; acc[1][3]+=v4.y*p4.w;
      acc[2][0]+=v4.z*p4.x; acc[2][1]+=v4.z*p4.y; acc[2][2]+=v4.z*p4.z; acc[2][3]+=v4.z*p4.w;
      acc[3][0]+=v4.w*p4.x; acc[3][1]+=v4.w*p4.y; acc[3][2]+=v4.w*p4.z; acc[3][3]+=v4.w*p4.w;
    }
    __syncthreads();
  }
  #pragma unroll
  for (int ci = 0; ci < 4; ci++){
    int c = cg*4 + ci;
    float4 o; o.x = acc[ci][0]; o.y = acc[ci][1]; o.z = acc[ci][2]; o.w = acc[ci][3];
    *(float4*)(wsp + OFF_SAP + (((size_t)ns*2 + b)*64 + c)*2304 + mbase + mg*4) = o;
  }
}

// ---------------- K7: sa = gamma * sum(partials) + s ----------------
__global__ __launch_bounds__(256) void k_sacomb(float* __restrict__ wsp, const float* __restrict__ gamma){
  size_t i = (size_t)blockIdx.x*256 + threadIdx.x;   // 294912 elems
  float g = gamma[0];
  float p = wsp[OFF_SAP + i] + wsp[OFF_SAP + 294912 + i]
          + wsp[OFF_SAP + 2*294912 + i] + wsp[OFF_SAP + 3*294912 + i];
  wsp[OFF_SA + i] = g*p + wsp[OFF_S + i];
}

// ---------------- K8: bilinear upsample gc branches (align_corners=True) ----------------
__global__ __launch_bounds__(256) void k_gcup(float* __restrict__ wsp){
  int px = blockIdx.x*256 + threadIdx.x;   // 0..2303
  int pb = blockIdx.y;                     // t*128 + b*64 + c
  int c = pb & 63, b = (pb >> 6) & 1, t = pb >> 7;
  int oy = px / 48, ox = px - oy*48;
  int ps; const float* g;
  if (t == 0){ ps = 1; g = wsp + OFF_G0 + (size_t)b*64; }
  else if (t == 1){ ps = 3; g = wsp + OFF_G1 + (size_t)b*9*64; }
  else { ps = 5; g = wsp + OFF_G2 + (size_t)b*25*64; }
  float scale = (ps - 1) / 47.f;
  float cy = oy*scale, cx = ox*scale;
  int y0 = (int)cy, x0 = (int)cx;
  float wy = cy - y0, wx = cx - x0;
  int y1 = min(y0+1, ps-1), x1 = min(x0+1, ps-1);
  float a  = g[(y0*ps+x0)*64 + c], bq = g[(y0*ps+x1)*64 + c];
  float cc = g[(y1*ps+x0)*64 + c], d  = g[(y1*ps+x1)*64 + c];
  float v = (a*(1.f-wx) + bq*wx)*(1.f-wy) + (cc*(1.f-wx) + d*wx)*wy;
  wsp[OFF_GC + (((size_t)t*2 + b)*64 + c)*2304 + px] = v;
}

// ---------------- K9: spatial means of gcs0..2 and sa ----------------
__global__ __launch_bounds__(256) void k_gap(float* __restrict__ wsp){
  __shared__ float red[4];
  int blk = blockIdx.x; int c = blk & 63, b = (blk >> 6) & 1, t = blk >> 7;
  const float* src = (t < 3) ? wsp + OFF_GC + (((size_t)t*2 + b)*64 + c)*2304
                             : wsp + OFF_SA + ((size_t)b*64 + c)*2304;
  float s = 0.f;
  for (int i = threadIdx.x; i < 2304; i += 256) s += src[i];
  #pragma unroll
  for (int o = 32; o; o >>= 1) s += __shfl_xor(s, o);
  if ((threadIdx.x & 63) == 0) red[threadIdx.x >> 6] = s;
  __syncthreads();
  if (threadIdx.x == 0)
    wsp[OFF_MEAN + ((size_t)b*4 + t)*64 + c] = (red[0]+red[1]+red[2]+red[3]) * (1.f/2304.f);
}

// ---------------- K10: SE matvecs + sigmoid + softmax over 4 slots ----------------
__global__ __launch_bounds__(256) void k_se(
    const float* __restrict__ w_se1, const float* __restrict__ w_se2,
    const float* __restrict__ w_se3, const float* __restrict__ w_se4,
    float* __restrict__ wsp){
  int b = blockIdx.x; int tid = threadIdx.x;
  int g = tid >> 6, c = tid & 63;
  const float* w; int srct;
  if (g == 0){ w = w_se1; srct = 3; }        // slot0 = w_se1 . mean(sa)
  else if (g == 1){ w = w_se2; srct = 2; }   // slot1 = w_se2 . mean(gcs2)
  else if (g == 2){ w = w_se3; srct = 1; }   // slot2 = w_se3 . mean(gcs1)
  else { w = w_se4; srct = 0; }              // slot3 = w_se4 . mean(gcs0)
  const float* mean = wsp + OFF_MEAN + ((size_t)b*4 + srct)*64;
  float acc = 0.f;
  for (int j = 0; j < 64; j++) acc += w[(size_t)c*64 + j]*mean[j];
  float sg = 1.f / (1.f + __expf(-acc));
  __shared__ float sh[4][64];
  sh[g][c] = sg;
  __syncthreads();
  float a0 = sh[0][c], a1 = sh[1][c], a2 = sh[2][c], a3 = sh[3][c];
  float mx = fmaxf(fmaxf(a0, a1), fmaxf(a2, a3));
  float e = __expf(sg - mx);
  float sum = __expf(a0-mx) + __expf(a1-mx) + __expf(a2-mx) + __expf(a3-mx);
  wsp[OFF_WGT + ((size_t)b*4 + g)*64 + c] = e / sum;
}

// ---------------- K11: fused = wgt-scaled concat ----------------
__global__ __launch_bounds__(256) void k_fused(float* __restrict__ wsp){
  int px = blockIdx.x*256 + threadIdx.x;
  int by = blockIdx.y; int b = by >> 8, ch = by & 255, g = ch >> 6, c = ch & 63;
  float w = wsp[OFF_WGT + ((size_t)b*4 + g)*64 + c];
  const float* src = (g < 3) ? wsp + OFF_GC + (((size_t)g*2 + b)*64 + c)*2304
                             : wsp + OFF_SA + ((size_t)b*64 + c)*2304;
  wsp[OFF_FUSED + ((size_t)b*256 + ch)*2304 + px] = w*src[px];
}

// ---------------- K12: out-head GEMMs y = relu(W.fused + b), 512 rows, K=256 ----------------
__global__ __launch_bounds__(256) void k_outgemm(
    const float* __restrict__ w0, const float* __restrict__ b0,
    const float* __restrict__ w1, const float* __restrict__ b1,
    const float* __restrict__ w2, const float* __restrict__ b2,
    const float* __restrict__ w3, const float* __restrict__ b3,
    float* __restrict__ wsp){
  __shared__ __align__(16) float wt[64][68];
  int cb = blockIdx.x, rb = blockIdx.y;
  int b = cb / 36, hw0 = (cb - b*36)*64;
  const float* wsrc; const float* bsrc; size_t dstoff; int dstC; int row0;
  if (rb < 4){ wsrc = w0 + (size_t)rb*64*256; bsrc = b0 + rb*64; dstoff = OFF_Y0; dstC = 256; row0 = rb*64; }
  else if (rb < 6){ wsrc = w1 + (size_t)(rb-4)*64*256; bsrc = b1 + (rb-4)*64; dstoff = OFF_Y1; dstC = 128; row0 = (rb-4)*64; }
  else if (rb == 6){ wsrc = w2; bsrc = b2; dstoff = OFF_Y2; dstC = 64; row0 = 0; }
  else { wsrc = w3; bsrc = b3; dstoff = OFF_Y3; dstC = 64; row0 = 0; }
  int tid = threadIdx.x;
  int sr = tid >> 2, sseg = tid & 3;
  int cc0 = (tid & 15)*4, r0 = (tid >> 4)*4;
  const float* fb = wsp + OFF_FUSED + (size_t)b*256*2304 + hw0 + cc0;
  float acc[4][4] = {};
  for (int kc = 0; kc < 256; kc += 64){
    __syncthreads();
    #pragma unroll
    for (int i = 0; i < 16; i += 4){
      float4 v = *(const float4*)(wsrc + (size_t)sr*256 + kc + sseg*16 + i);
      wt[sseg*16+i+0][sr]=v.x; wt[sseg*16+i+1][sr]=v.y;
      wt[sseg*16+i+2][sr]=v.z; wt[sseg*16+i+3][sr]=v.w;
    }
    __syncthreads();
    const float* fk = fb + (size_t)kc*2304;
    #pragma unroll 4
    for (int k = 0; k < 64; k++){
      float4 wv = *(const float4*)&wt[k][r0];
      float4 xv = *(const float4*)(fk + (size_t)k*2304);
      acc[0][0]+=wv.x*xv.x; acc[0][1]+=wv.x*xv.y; acc[0][2]+=wv.x*xv.z; acc[0][3]+=wv.x*xv.w;
      acc[1][0]+=wv.y*xv.x; acc[1][1]+=wv.y*xv.y; acc[1][2]+=wv.y*xv.z; acc[1][3]+=wv.y*xv.w;
      acc[2][0]+=wv.z*xv.x; acc[2][1]+=wv.z*xv.y; acc[2][2]+=wv.z*xv.z; acc[2][3]+=wv.z*xv.w;
      acc[3][0]+=wv.w*xv.x; acc[3][1]+=wv.w*xv.y; acc[3][2]+=wv.w*xv.z; acc[3][3]+=wv.w*xv.w;
    }
  }
  #pragma unroll
  for (int i = 0; i < 4; i++){
    float bi = bsrc[r0+i];
    float4 o;
    o.x = fmaxf(acc[i][0]+bi, 0.f); o.y = fmaxf(acc[i][1]+bi, 0.f);
    o.z = fmaxf(acc[i][2]+bi, 0.f); o.w = fmaxf(acc[i][3]+bi, 0.f);
    *(float4*)(wsp + dstoff + ((size_t)b*dstC + row0 + r0 + i)*2304 + hw0 + cc0) = o;
  }
}

// ---------------- K13: bilinear upsample outputs (align_corners=False) ----------------
template<int SC, int CC>
__global__ __launch_bounds__(256) void k_upsample(const float* __restrict__ src, float* __restrict__ dst){
  constexpr int OW = 48*SC, OH = 48*SC;
  constexpr int WQ = OW/4;
  int tid = blockIdx.x*256 + threadIdx.x;
  int q = tid % WQ; int rest = tid / WQ;
  int oy = rest % OH; int pc = rest / OH;       // pc = b*CC + c
  if (pc >= 2*CC) return;
  const float* sp = src + (size_t)pc * 2304;
  float cy = fminf(fmaxf((oy + 0.5f)*(1.0f/SC) - 0.5f, 0.f), 47.f);
  int y0 = (int)cy;
  float wy = cy - y0;
  int y1 = min(y0+1, 47);
  const float* r0 = sp + y0*48; const float* r1 = sp + y1*48;
  float4 o;
  float outv[4];
  #pragma unroll
  for (int i = 0; i < 4; i++){
    int ox = q*4 + i;
    float cx = fminf(fmaxf((ox + 0.5f)*(1.0f/SC) - 0.5f, 0.f), 47.f);
    int x0 = (int)cx; float wx = cx - x0; int x1 = min(x0+1, 47);
    float a  = r0[x0]*(1.f-wx) + r0[x1]*wx;
    float bq = r1[x0]*(1.f-wx) + r1[x1]*wx;
    outv[i] = a*(1.f-wy) + bq*wy;
  }
  o.x = outv[0]; o.y = outv[1]; o.z = outv[2]; o.w = outv[3];
  *(float4*)(dst + (size_t)pc*OH*OW + (size_t)oy*OW + q*4) = o;
}

// ---------------- launcher ----------------
extern "C" void kernel_launch(void* const* d_in, const int* in_sizes, int n_in,
                              void* d_out, int out_size, void* d_ws, size_t ws_size,
                              hipStream_t stream){
  const float* x     = (const float*)d_in[0];
  const float* w_gc0 = (const float*)d_in[1];
  const float* b_gc0 = (const float*)d_in[2];
  const float* w_gc1 = (const float*)d_in[3];
  const float* b_gc1 = (const float*)d_in[4];
  const float* w_gc2 = (const float*)d_in[5];
  const float* b_gc2 = (const float*)d_in[6];
  const float* w_gc3 = (const float*)d_in[7];
  const float* b_gc3 = (const float*)d_in[8];
  const float* w_q   = (const float*)d_in[9];
  const float* b_q   = (const float*)d_in[10];
  const float* w_k   = (const float*)d_in[11];
  const float* b_k   = (const float*)d_in[12];
  const float* w_v   = (const float*)d_in[13];
  const float* b_v   = (const float*)d_in[14];
  const float* gamma = (const float*)d_in[15];
  const float* w_se1 = (const float*)d_in[16];
  const float* w_se2 = (const float*)d_in[17];
  const float* w_se3 = (const float*)d_in[18];
  const float* w_se4 = (const float*)d_in[19];
  const float* w_out0 = (const float*)d_in[20];
  const float* b_out0 = (const float*)d_in[21];
  const float* w_out1 = (const float*)d_in[22];
  const float* b_out1 = (const float*)d_in[23];
  const float* w_out2 = (const float*)d_in[24];
  const float* b_out2 = (const float*)d_in[25];
  const float* w_out3 = (const float*)d_in[26];
  const float* b_out3 = (const float*)d_in[27];
  float* wsp = (float*)d_ws;
  float* out = (float*)d_out;

  k_pool   <<<1024, 256, 0, stream>>>(x, wsp);
  k_gcconv <<<70,   256, 0, stream>>>(w_gc0,b_gc0,w_gc1,b_gc1,w_gc2,b_gc2, wsp);
  k_sgemm  <<<72,   256, 0, stream>>>(x, w_gc3, b_gc3, wsp);
  k_qkv    <<<dim3(18,5), 256, 0, stream>>>(w_q,b_q,w_k,b_k,w_v,b_v, wsp);
  k_softmax<<<4608, 256, 0, stream>>>(wsp);
  k_pv     <<<dim3(36,2,4), 256, 0, stream>>>(wsp);
  k_sacomb <<<1152, 256, 0, stream>>>(wsp, gamma);
  k_gcup   <<<dim3(9,384), 256, 0, stream>>>(wsp);
  k_gap    <<<512,  256, 0, stream>>>(wsp);
  k_se     <<<2,    256, 0, stream>>>(w_se1,w_se2,w_se3,w_se4, wsp);
  k_fused  <<<dim3(9,512), 256, 0, stream>>>(wsp);
  k_outgemm<<<dim3(72,8), 256, 0, stream>>>(w_out0,b_out0,w_out1,b_out1,w_out2,b_out2,w_out3,b_out3, wsp);
  k_upsample<2,256><<<4608,  256, 0, stream>>>(wsp + OFF_Y0, out);
  k_upsample<4,128><<<9216,  256, 0, stream>>>(wsp + OFF_Y1, out + 4718592);
  k_upsample<8,64> <<<18432, 256, 0, stream>>>(wsp + OFF_Y2, out + 14155776);
  k_upsample<16,64><<<73728, 256, 0, stream>>>(wsp + OFF_Y3, out + 33030144);
}

// Round 2
// 303.544 us; speedup vs baseline: 1.0157x; 1.0157x over previous
//
#include <hip/hip_runtime.h>
#include <hip/hip_bf16.h>

// ---------------- problem dims ----------------
// B=2, Cin=512, C=64, H=W=48, N=2304 spatial, 4608 total columns.

typedef __attribute__((ext_vector_type(8))) short short8;
typedef __attribute__((ext_vector_type(4))) float f32x4;

// ---------------- ws layout (float offsets) ----------------
static constexpr size_t OFF_P1 = 0;                       // [2][512] pooled ps=1
static constexpr size_t OFF_P3 = OFF_P1 + 2*512;          // [2*9][512]
static constexpr size_t OFF_P5 = OFF_P3 + 18*512;         // [2*25][512]
static constexpr size_t OFF_G0 = OFF_P5 + 50*512;         // [2*1][64]
static constexpr size_t OFF_G1 = OFF_G0 + 2*64;           // [2*9][64]
static constexpr size_t OFF_G2 = OFF_G1 + 18*64;          // [2*25][64]
static constexpr size_t OFF_S  = OFF_G2 + 50*64;          // [2][64][2304] f32
static constexpr size_t OFF_Q  = OFF_S  + 294912;         // [2][8][2304] f32
static constexpr size_t OFF_K  = OFF_Q  + 36864;          // [2][8][2304] f32
static constexpr size_t OFF_V  = OFF_K  + 36864;          // bf16 [2][64][2304] (region sized for f32)
static constexpr size_t OFF_SAP= OFF_V  + 294912;         // (unused now)
static constexpr size_t OFF_SA = OFF_SAP+ 4*294912;       // [2][64][2304] f32
static constexpr size_t OFF_GC = OFF_SA + 294912;         // [3][2][64][2304] f32
static constexpr size_t OFF_MEAN = OFF_GC + 3*294912;     // [2][4][64]
static constexpr size_t OFF_WGT  = OFF_MEAN + 512;        // [2][4][64]
static constexpr size_t OFF_FUSED= OFF_WGT + 512;         // [2][256][2304] f32
static constexpr size_t OFF_Y0 = OFF_FUSED + 1179648;     // [2][256][2304]
static constexpr size_t OFF_Y1 = OFF_Y0 + 1179648;        // [2][128][2304]
static constexpr size_t OFF_Y2 = OFF_Y1 + 589824;         // [2][64][2304]
static constexpr size_t OFF_Y3 = OFF_Y2 + 294912;         // [2][64][2304]
static constexpr size_t OFF_PA = OFF_Y3 + 294912;         // bf16 [2][2304][2304] attn probs

// ---------------- K1: adaptive pools (1,3,5) ----------------
__global__ __launch_bounds__(256) void k_pool(const float* __restrict__ x, float* __restrict__ wsp){
  __shared__ float pl[2304];
  __shared__ float red[4];
  int bc = blockIdx.x;            // b*512 + cin
  int b = bc >> 9, cin = bc & 511;
  const float* src = x + (size_t)bc * 2304;
  int t = threadIdx.x;
  float ls = 0.f;
  #pragma unroll
  for (int j = 0; j < 9; j++){ int i = t + j*256; float v = src[i]; pl[i] = v; ls += v; }
  #pragma unroll
  for (int o = 32; o; o >>= 1) ls += __shfl_xor(ls, o);
  if ((t & 63) == 0) red[t >> 6] = ls;
  __syncthreads();
  if (t == 0) wsp[OFF_P1 + (size_t)b*512 + cin] = (red[0]+red[1]+red[2]+red[3]) * (1.f/2304.f);
  if (t < 9){
    int ry = t/3, rx = t%3; float sm = 0.f;
    for (int yy = 0; yy < 16; yy++)
      for (int xx = 0; xx < 16; xx++) sm += pl[(ry*16+yy)*48 + rx*16+xx];
    wsp[OFF_P3 + ((size_t)b*9 + t)*512 + cin] = sm * (1.f/256.f);
  } else if (t < 34){
    int j = t - 9; int ry = j/5, rx = j%5;
    int hs = (ry*48)/5, he = ((ry+1)*48+4)/5, cs = (rx*48)/5, ce = ((rx+1)*48+4)/5;
    float sm = 0.f;
    for (int yy = hs; yy < he; yy++)
      for (int xx = cs; xx < ce; xx++) sm += pl[yy*48+xx];
    wsp[OFF_P5 + ((size_t)b*25 + j)*512 + cin] = sm / (float)((he-hs)*(ce-cs));
  }
}

// ---------------- K2: tiny 64x512 convs on pooled cols ----------------
__global__ __launch_bounds__(256) void k_gcconv(
    const float* __restrict__ w0, const float* __restrict__ b0,
    const float* __restrict__ w1, const float* __restrict__ b1,
    const float* __restrict__ w2, const float* __restrict__ b2,
    float* __restrict__ wsp){
  int col = blockIdx.x;          // 0..69 : 2 + 18 + 50
  const float* w; const float* bias; const float* pool; float* dst;
  if (col < 2){ w = w0; bias = b0; pool = wsp + OFF_P1 + (size_t)col*512; dst = wsp + OFF_G0 + (size_t)col*64; }
  else if (col < 20){ int c = col-2;  w = w1; bias = b1; pool = wsp + OFF_P3 + (size_t)c*512; dst = wsp + OFF_G1 + (size_t)c*64; }
  else              { int c = col-20; w = w2; bias = b2; pool = wsp + OFF_P5 + (size_t)c*512; dst = wsp + OFF_G2 + (size_t)c*64; }
  int t = threadIdx.x; int r = t >> 2, qd = t & 3;
  const float* wr = w + (size_t)r*512 + qd*128;
  const float* pr = pool + qd*128;
  float acc = 0.f;
  #pragma unroll 8
  for (int k = 0; k < 128; k += 4){
    float4 wv = *(const float4*)(wr + k); float4 pv = *(const float4*)(pr + k);
    acc += wv.x*pv.x + wv.y*pv.y + wv.z*pv.z + wv.w*pv.w;
  }
  acc += __shfl_xor(acc, 1); acc += __shfl_xor(acc, 2);
  if (qd == 0) dst[r] = fmaxf(acc + bias[r], 0.f);
}

// ---------------- K3: s = relu(Wgc3 . x + b)  M=64,K=512,N=4608 ----------------
__global__ __launch_bounds__(256) void k_sgemm(const float* __restrict__ x,
    const float* __restrict__ w, const float* __restrict__ bias, float* __restrict__ wsp){
  __shared__ __align__(16) float wt[64][68];   // [k][r] transposed chunk
  int cb = blockIdx.x;                          // 72: b*36 + coltile
  int b = cb / 36, hw0 = (cb - b*36)*64;
  int tid = threadIdx.x;
  int sr = tid >> 2, sseg = tid & 3;
  int cc0 = (tid & 15)*4, r0 = (tid >> 4)*4;
  const float* xb = x + (size_t)b*512*2304 + hw0 + cc0;
  float acc[4][4] = {};
  for (int kc = 0; kc < 512; kc += 64){
    __syncthreads();
    #pragma unroll
    for (int i = 0; i < 16; i += 4){
      float4 v = *(const float4*)(w + (size_t)sr*512 + kc + sseg*16 + i);
      wt[sseg*16+i+0][sr]=v.x; wt[sseg*16+i+1][sr]=v.y;
      wt[sseg*16+i+2][sr]=v.z; wt[sseg*16+i+3][sr]=v.w;
    }
    __syncthreads();
    const float* xk = xb + (size_t)kc*2304;
    #pragma unroll 4
    for (int k = 0; k < 64; k++){
      float4 wv = *(const float4*)&wt[k][r0];
      float4 xv = *(const float4*)(xk + (size_t)k*2304);
      acc[0][0]+=wv.x*xv.x; acc[0][1]+=wv.x*xv.y; acc[0][2]+=wv.x*xv.z; acc[0][3]+=wv.x*xv.w;
      acc[1][0]+=wv.y*xv.x; acc[1][1]+=wv.y*xv.y; acc[1][2]+=wv.y*xv.z; acc[1][3]+=wv.y*xv.w;
      acc[2][0]+=wv.z*xv.x; acc[2][1]+=wv.z*xv.y; acc[2][2]+=wv.z*xv.z; acc[2][3]+=wv.z*xv.w;
      acc[3][0]+=wv.w*xv.x; acc[3][1]+=wv.w*xv.y; acc[3][2]+=wv.w*xv.z; acc[3][3]+=wv.w*xv.w;
    }
  }
  #pragma unroll
  for (int i = 0; i < 4; i++){
    float bi = bias[r0+i];
    float4 o;
    o.x = fmaxf(acc[i][0]+bi, 0.f); o.y = fmaxf(acc[i][1]+bi, 0.f);
    o.z = fmaxf(acc[i][2]+bi, 0.f); o.w = fmaxf(acc[i][3]+bi, 0.f);
    *(float4*)(wsp + OFF_S + ((size_t)b*64 + r0+i)*2304 + hw0 + cc0) = o;
  }
}

// ---------------- K4: q,k,v projections (80 rows, K=64); V stored bf16 ----------------
__global__ __launch_bounds__(256) void k_qkv(
    const float* __restrict__ wq, const float* __restrict__ bq,
    const float* __restrict__ wk, const float* __restrict__ bk,
    const float* __restrict__ wv, const float* __restrict__ bv,
    float* __restrict__ wsp){
  __shared__ float wl[16][64];
  __shared__ float bl[16];
  int tid = threadIdx.x;
  int rg = blockIdx.y;                   // 5 row groups of 16
  for (int i = tid; i < 1024; i += 256){
    int r = i >> 6, k = i & 63;
    int gr = rg*16 + r;
    const float* w = (gr < 8) ? (wq + (size_t)gr*64) : (gr < 16 ? wk + (size_t)(gr-8)*64 : wv + (size_t)(gr-16)*64);
    wl[r][k] = w[k];
  }
  if (tid < 16){
    int gr = rg*16 + tid;
    bl[tid] = (gr < 8) ? bq[gr] : (gr < 16 ? bk[gr-8] : bv[gr-16]);
  }
  __syncthreads();
  int col = blockIdx.x*256 + tid;        // 0..4607
  int b = col / 2304; int hw = col - b*2304;
  const float* sp = wsp + OFF_S + (size_t)b*147456 + hw;
  float acc[16];
  #pragma unroll
  for (int r = 0; r < 16; r++) acc[r] = bl[r];
  for (int k = 0; k < 64; k++){
    float sv = sp[(size_t)k*2304];
    #pragma unroll
    for (int r = 0; r < 16; r++) acc[r] += wl[r][k]*sv;
  }
  __hip_bfloat16* Vb = reinterpret_cast<__hip_bfloat16*>(wsp + OFF_V);
  #pragma unroll
  for (int r = 0; r < 16; r++){
    int gr = rg*16 + r;
    if (gr < 8)       wsp[OFF_Q + (size_t)b*18432 + (size_t)gr*2304 + hw] = acc[r];
    else if (gr < 16) wsp[OFF_K + (size_t)b*18432 + (size_t)(gr-8)*2304 + hw] = acc[r];
    else              Vb[(size_t)b*147456 + (size_t)(gr-16)*2304 + hw] = __float2bfloat16(acc[r]);
  }
}

// ---------------- K5: attention logits + softmax -> P (bf16), 8 rows/block ----------------
__global__ __launch_bounds__(256) void k_softmax(float* __restrict__ wsp){
  int blk = blockIdx.x;           // 576
  int row0 = blk * 8;
  int b = row0 / 2304, m0 = row0 - b*2304;
  const float* kk = wsp + OFF_K + (size_t)b*18432;
  __shared__ float qs[8][9];
  __shared__ float redm[4][8], reds[4][8];
  int t = threadIdx.x;
  if (t < 64) qs[t>>3][t&7] = wsp[OFF_Q + (size_t)b*18432 + (size_t)(t&7)*2304 + m0 + (t>>3)];
  __syncthreads();
  float l[9][8];
  #pragma unroll
  for (int j = 0; j < 9; j++){
    int n = t + j*256;
    float k8[8];
    #pragma unroll
    for (int c = 0; c < 8; c++) k8[c] = kk[(size_t)c*2304 + n];
    #pragma unroll
    for (int m = 0; m < 8; m++){
      float a = 0.f;
      #pragma unroll
      for (int c = 0; c < 8; c++) a += qs[m][c]*k8[c];
      l[j][m] = a;
    }
  }
  int w = t >> 6, lane = t & 63;
  float mx[8];
  #pragma unroll
  for (int m = 0; m < 8; m++){
    float v = l[0][m];
    #pragma unroll
    for (int j = 1; j < 9; j++) v = fmaxf(v, l[j][m]);
    #pragma unroll
    for (int o = 32; o; o >>= 1) v = fmaxf(v, __shfl_xor(v, o));
    mx[m] = v;
  }
  if (lane == 0){
    #pragma unroll
    for (int m = 0; m < 8; m++) redm[w][m] = mx[m];
  }
  __syncthreads();
  float Mm[8];
  #pragma unroll
  for (int m = 0; m < 8; m++)
    Mm[m] = fmaxf(fmaxf(redm[0][m], redm[1][m]), fmaxf(redm[2][m], redm[3][m]));
  float sm[8];
  #pragma unroll
  for (int m = 0; m < 8; m++){
    float s = 0.f;
    #pragma unroll
    for (int j = 0; j < 9; j++){ l[j][m] = __expf(l[j][m]-Mm[m]); s += l[j][m]; }
    #pragma unroll
    for (int o = 32; o; o >>= 1) s += __shfl_xor(s, o);
    sm[m] = s;
  }
  if (lane == 0){
    #pragma unroll
    for (int m = 0; m < 8; m++) reds[w][m] = sm[m];
  }
  __syncthreads();
  __hip_bfloat16* Pp = reinterpret_cast<__hip_bfloat16*>(wsp + OFF_PA);
  #pragma unroll
  for (int m = 0; m < 8; m++){
    float inv = 1.f / (reds[0][m]+reds[1][m]+reds[2][m]+reds[3][m]);
    #pragma unroll
    for (int j = 0; j < 9; j++){
      int n = t + j*256;
      Pp[(size_t)(b*2304 + m0 + m)*2304 + n] = __float2bfloat16(l[j][m]*inv);
    }
  }
}

// ---------------- K6: sa = gamma*(P.V^T) + s via MFMA bf16 ----------------
// Per block: 16 m-rows x 64 c.  wave w -> c-block w*16.  K-loop over n (2304/32).
// A-frag: P[m = mb+(lane&15)][n = nb+(lane>>4)*8 .. +7]   (16B lane-local load)
// B-frag: V[c = w*16+(lane&15)][n = nb+(lane>>4)*8 .. +7] (16B lane-local load)
// D: col=c=lane&15(+w*16), row=m=(lane>>4)*4+reg  [guide m89 layout]
__global__ __launch_bounds__(256) void k_pv(float* __restrict__ wsp, const float* __restrict__ gamma){
  int mb = blockIdx.x * 16;      // 144 m-tiles
  int b  = blockIdx.y;
  int t = threadIdx.x;
  int w = t >> 6, lane = t & 63;
  int arow = lane & 15, kg = lane >> 4;
  const short* P = (const short*)(wsp + OFF_PA) + (size_t)(b*2304 + mb + arow)*2304 + kg*8;
  const short* V = (const short*)(wsp + OFF_V) + (size_t)b*147456 + (size_t)(w*16 + arow)*2304 + kg*8;
  f32x4 acc = {0.f, 0.f, 0.f, 0.f};
  for (int nb = 0; nb < 2304; nb += 32){
    short8 a  = *(const short8*)(P + nb);
    short8 bf = *(const short8*)(V + nb);
    acc = __builtin_amdgcn_mfma_f32_16x16x32_bf16(a, bf, acc, 0, 0, 0);
  }
  __shared__ float tile[16][68];
  #pragma unroll
  for (int r = 0; r < 4; r++) tile[kg*4 + r][w*16 + arow] = acc[r];
  __syncthreads();
  int c = t >> 2, mq = t & 3;
  float g = gamma[0];
  const float* Sp = wsp + OFF_S + (size_t)b*147456 + (size_t)c*2304 + mb + mq*4;
  float4 s4 = *(const float4*)Sp;
  float4 o;
  o.x = g*tile[mq*4+0][c] + s4.x;
  o.y = g*tile[mq*4+1][c] + s4.y;
  o.z = g*tile[mq*4+2][c] + s4.z;
  o.w = g*tile[mq*4+3][c] + s4.w;
  *(float4*)(wsp + OFF_SA + (size_t)b*147456 + (size_t)c*2304 + mb + mq*4) = o;
}

// ---------------- K8: bilinear upsample gc branches (align_corners=True) ----------------
__global__ __launch_bounds__(256) void k_gcup(float* __restrict__ wsp){
  int px = blockIdx.x*256 + threadIdx.x;   // 0..2303
  int pb = blockIdx.y;                     // t*128 + b*64 + c
  int c = pb & 63, b = (pb >> 6) & 1, t = pb >> 7;
  int oy = px / 48, ox = px - oy*48;
  int ps; const float* g;
  if (t == 0){ ps = 1; g = wsp + OFF_G0 + (size_t)b*64; }
  else if (t == 1){ ps = 3; g = wsp + OFF_G1 + (size_t)b*9*64; }
  else { ps = 5; g = wsp + OFF_G2 + (size_t)b*25*64; }
  float scale = (ps - 1) / 47.f;
  float cy = oy*scale, cx = ox*scale;
  int y0 = (int)cy, x0 = (int)cx;
  float wy = cy - y0, wx = cx - x0;
  int y1 = min(y0+1, ps-1), x1 = min(x0+1, ps-1);
  float a  = g[(y0*ps+x0)*64 + c], bq = g[(y0*ps+x1)*64 + c];
  float cc = g[(y1*ps+x0)*64 + c], d  = g[(y1*ps+x1)*64 + c];
  float v = (a*(1.f-wx) + bq*wx)*(1.f-wy) + (cc*(1.f-wx) + d*wx)*wy;
  wsp[OFF_GC + (((size_t)t*2 + b)*64 + c)*2304 + px] = v;
}

// ---------------- K9: spatial means of gcs0..2 and sa ----------------
__global__ __launch_bounds__(256) void k_gap(float* __restrict__ wsp){
  __shared__ float red[4];
  int blk = blockIdx.x; int c = blk & 63, b = (blk >> 6) & 1, t = blk >> 7;
  const float* src = (t < 3) ? wsp + OFF_GC + (((size_t)t*2 + b)*64 + c)*2304
                             : wsp + OFF_SA + ((size_t)b*64 + c)*2304;
  float s = 0.f;
  for (int i = threadIdx.x; i < 2304; i += 256) s += src[i];
  #pragma unroll
  for (int o = 32; o; o >>= 1) s += __shfl_xor(s, o);
  if ((threadIdx.x & 63) == 0) red[threadIdx.x >> 6] = s;
  __syncthreads();
  if (threadIdx.x == 0)
    wsp[OFF_MEAN + ((size_t)b*4 + t)*64 + c] = (red[0]+red[1]+red[2]+red[3]) * (1.f/2304.f);
}

// ---------------- K10: SE matvecs + sigmoid + softmax over 4 slots ----------------
__global__ __launch_bounds__(256) void k_se(
    const float* __restrict__ w_se1, const float* __restrict__ w_se2,
    const float* __restrict__ w_se3, const float* __restrict__ w_se4,
    float* __restrict__ wsp){
  int b = blockIdx.x; int tid = threadIdx.x;
  int g = tid >> 6, c = tid & 63;
  const float* w; int srct;
  if (g == 0){ w = w_se1; srct = 3; }
  else if (g == 1){ w = w_se2; srct = 2; }
  else if (g == 2){ w = w_se3; srct = 1; }
  else { w = w_se4; srct = 0; }
  const float* mean = wsp + OFF_MEAN + ((size_t)b*4 + srct)*64;
  float acc = 0.f;
  for (int j = 0; j < 64; j++) acc += w[(size_t)c*64 + j]*mean[j];
  float sg = 1.f / (1.f + __expf(-acc));
  __shared__ float sh[4][64];
  sh[g][c] = sg;
  __syncthreads();
  float a0 = sh[0][c], a1 = sh[1][c], a2 = sh[2][c], a3 = sh[3][c];
  float mxv = fmaxf(fmaxf(a0, a1), fmaxf(a2, a3));
  float e = __expf(sg - mxv);
  float sum = __expf(a0-mxv) + __expf(a1-mxv) + __expf(a2-mxv) + __expf(a3-mxv);
  wsp[OFF_WGT + ((size_t)b*4 + g)*64 + c] = e / sum;
}

// ---------------- K11: fused = wgt-scaled concat ----------------
__global__ __launch_bounds__(256) void k_fused(float* __restrict__ wsp){
  int px = blockIdx.x*256 + threadIdx.x;
  int by = blockIdx.y; int b = by >> 8, ch = by & 255, g = ch >> 6, c = ch & 63;
  float w = wsp[OFF_WGT + ((size_t)b*4 + g)*64 + c];
  const float* src = (g < 3) ? wsp + OFF_GC + (((size_t)g*2 + b)*64 + c)*2304
                             : wsp + OFF_SA + ((size_t)b*64 + c)*2304;
  wsp[OFF_FUSED + ((size_t)b*256 + ch)*2304 + px] = w*src[px];
}

// ---------------- K12: out-head GEMMs y = relu(W.fused + b), 512 rows, K=256 ----------------
__global__ __launch_bounds__(256) void k_outgemm(
    const float* __restrict__ w0, const float* __restrict__ b0,
    const float* __restrict__ w1, const float* __restrict__ b1,
    const float* __restrict__ w2, const float* __restrict__ b2,
    const float* __restrict__ w3, const float* __restrict__ b3,
    float* __restrict__ wsp){
  __shared__ __align__(16) float wt[64][68];
  int cb = blockIdx.x, rb = blockIdx.y;
  int b = cb / 36, hw0 = (cb - b*36)*64;
  const float* wsrc; const float* bsrc; size_t dstoff; int dstC; int row0;
  if (rb < 4){ wsrc = w0 + (size_t)rb*64*256; bsrc = b0 + rb*64; dstoff = OFF_Y0; dstC = 256; row0 = rb*64; }
  else if (rb < 6){ wsrc = w1 + (size_t)(rb-4)*64*256; bsrc = b1 + (rb-4)*64; dstoff = OFF_Y1; dstC = 128; row0 = (rb-4)*64; }
  else if (rb == 6){ wsrc = w2; bsrc = b2; dstoff = OFF_Y2; dstC = 64; row0 = 0; }
  else { wsrc = w3; bsrc = b3; dstoff = OFF_Y3; dstC = 64; row0 = 0; }
  int tid = threadIdx.x;
  int sr = tid >> 2, sseg = tid & 3;
  int cc0 = (tid & 15)*4, r0 = (tid >> 4)*4;
  const float* fb = wsp + OFF_FUSED + (size_t)b*256*2304 + hw0 + cc0;
  float acc[4][4] = {};
  for (int kc = 0; kc < 256; kc += 64){
    __syncthreads();
    #pragma unroll
    for (int i = 0; i < 16; i += 4){
      float4 v = *(const float4*)(wsrc + (size_t)sr*256 + kc + sseg*16 + i);
      wt[sseg*16+i+0][sr]=v.x; wt[sseg*16+i+1][sr]=v.y;
      wt[sseg*16+i+2][sr]=v.z; wt[sseg*16+i+3][sr]=v.w;
    }
    __syncthreads();
    const float* fk = fb + (size_t)kc*2304;
    #pragma unroll 4
    for (int k = 0; k < 64; k++){
      float4 wv = *(const float4*)&wt[k][r0];
      float4 xv = *(const float4*)(fk + (size_t)k*2304);
      acc[0][0]+=wv.x*xv.x; acc[0][1]+=wv.x*xv.y; acc[0][2]+=wv.x*xv.z; acc[0][3]+=wv.x*xv.w;
      acc[1][0]+=wv.y*xv.x; acc[1][1]+=wv.y*xv.y; acc[1][2]+=wv.y*xv.z; acc[1][3]+=wv.y*xv.w;
      acc[2][0]+=wv.z*xv.x; acc[2][1]+=wv.z*xv.y; acc[2][2]+=wv.z*xv.z; acc[2][3]+=wv.z*xv.w;
      acc[3][0]+=wv.w*xv.x; acc[3][1]+=wv.w*xv.y; acc[3][2]+=wv.w*xv.z; acc[3][3]+=wv.w*xv.w;
    }
  }
  #pragma unroll
  for (int i = 0; i < 4; i++){
    float bi = bsrc[r0+i];
    float4 o;
    o.x = fmaxf(acc[i][0]+bi, 0.f); o.y = fmaxf(acc[i][1]+bi, 0.f);
    o.z = fmaxf(acc[i][2]+bi, 0.f); o.w = fmaxf(acc[i][3]+bi, 0.f);
    *(float4*)(wsp + dstoff + ((size_t)b*dstC + row0 + r0 + i)*2304 + hw0 + cc0) = o;
  }
}

// ---------------- K13: bilinear upsample outputs (align_corners=False) ----------------
template<int SC, int CC>
__global__ __launch_bounds__(256) void k_upsample(const float* __restrict__ src, float* __restrict__ dst){
  constexpr int OW = 48*SC, OH = 48*SC;
  constexpr int WQ = OW/4;
  int tid = blockIdx.x*256 + threadIdx.x;
  int q = tid % WQ; int rest = tid / WQ;
  int oy = rest % OH; int pc = rest / OH;       // pc = b*CC + c
  if (pc >= 2*CC) return;
  const float* sp = src + (size_t)pc * 2304;
  float cy = fminf(fmaxf((oy + 0.5f)*(1.0f/SC) - 0.5f, 0.f), 47.f);
  int y0 = (int)cy;
  float wy = cy - y0;
  int y1 = min(y0+1, 47);
  const float* r0 = sp + y0*48; const float* r1 = sp + y1*48;
  float4 o;
  float outv[4];
  #pragma unroll
  for (int i = 0; i < 4; i++){
    int ox = q*4 + i;
    float cx = fminf(fmaxf((ox + 0.5f)*(1.0f/SC) - 0.5f, 0.f), 47.f);
    int x0 = (int)cx; float wx = cx - x0; int x1 = min(x0+1, 47);
    float a  = r0[x0]*(1.f-wx) + r0[x1]*wx;
    float bq = r1[x0]*(1.f-wx) + r1[x1]*wx;
    outv[i] = a*(1.f-wy) + bq*wy;
  }
  o.x = outv[0]; o.y = outv[1]; o.z = outv[2]; o.w = outv[3];
  *(float4*)(dst + (size_t)pc*OH*OW + (size_t)oy*OW + q*4) = o;
}

// ---------------- launcher ----------------
extern "C" void kernel_launch(void* const* d_in, const int* in_sizes, int n_in,
                              void* d_out, int out_size, void* d_ws, size_t ws_size,
                              hipStream_t stream){
  const float* x     = (const float*)d_in[0];
  const float* w_gc0 = (const float*)d_in[1];
  const float* b_gc0 = (const float*)d_in[2];
  const float* w_gc1 = (const float*)d_in[3];
  const float* b_gc1 = (const float*)d_in[4];
  const float* w_gc2 = (const float*)d_in[5];
  const float* b_gc2 = (const float*)d_in[6];
  const float* w_gc3 = (const float*)d_in[7];
  const float* b_gc3 = (const float*)d_in[8];
  const float* w_q   = (const float*)d_in[9];
  const float* b_q   = (const float*)d_in[10];
  const float* w_k   = (const float*)d_in[11];
  const float* b_k   = (const float*)d_in[12];
  const float* w_v   = (const float*)d_in[13];
  const float* b_v   = (const float*)d_in[14];
  const float* gamma = (const float*)d_in[15];
  const float* w_se1 = (const float*)d_in[16];
  const float* w_se2 = (const float*)d_in[17];
  const float* w_se3 = (const float*)d_in[18];
  const float* w_se4 = (const float*)d_in[19];
  const float* w_out0 = (const float*)d_in[20];
  const float* b_out0 = (const float*)d_in[21];
  const float* w_out1 = (const float*)d_in[22];
  const float* b_out1 = (const float*)d_in[23];
  const float* w_out2 = (const float*)d_in[24];
  const float* b_out2 = (const float*)d_in[25];
  const float* w_out3 = (const float*)d_in[26];
  const float* b_out3 = (const float*)d_in[27];
  float* wsp = (float*)d_ws;
  float* out = (float*)d_out;

  k_pool   <<<1024, 256, 0, stream>>>(x, wsp);
  k_gcconv <<<70,   256, 0, stream>>>(w_gc0,b_gc0,w_gc1,b_gc1,w_gc2,b_gc2, wsp);
  k_sgemm  <<<72,   256, 0, stream>>>(x, w_gc3, b_gc3, wsp);
  k_qkv    <<<dim3(18,5), 256, 0, stream>>>(w_q,b_q,w_k,b_k,w_v,b_v, wsp);
  k_softmax<<<576,  256, 0, stream>>>(wsp);
  k_pv     <<<dim3(144,2), 256, 0, stream>>>(wsp, gamma);
  k_gcup   <<<dim3(9,384), 256, 0, stream>>>(wsp);
  k_gap    <<<512,  256, 0, stream>>>(wsp);
  k_se     <<<2,    256, 0, stream>>>(w_se1,w_se2,w_se3,w_se4, wsp);
  k_fused  <<<dim3(9,512), 256, 0, stream>>>(wsp);
  k_outgemm<<<dim3(72,8), 256, 0, stream>>>(w_out0,b_out0,w_out1,b_out1,w_out2,b_out2,w_out3,b_out3, wsp);
  k_upsample<2,256><<<4608,  256, 0, stream>>>(wsp + OFF_Y0, out);
  k_upsample<4,128><<<9216,  256, 0, stream>>>(wsp + OFF_Y1, out + 4718592);
  k_upsample<8,64> <<<18432, 256, 0, stream>>>(wsp + OFF_Y2, out + 14155776);
  k_upsample<16,64><<<73728, 256, 0, stream>>>(wsp + OFF_Y3, out + 33030144);
}

// Round 3
// 273.488 us; speedup vs baseline: 1.1273x; 1.1099x over previous
//
#include <hip/hip_runtime.h>
#include <hip/hip_bf16.h>

// B=2, Cin=512, C=64, H=W=48, N=2304 spatial, 4608 total columns.

typedef __attribute__((ext_vector_type(8))) short short8;
typedef __attribute__((ext_vector_type(4))) float f32x4;

// ---------------- ws layout (float offsets) ----------------
static constexpr size_t OFF_P1 = 0;                       // [2][512]
static constexpr size_t OFF_P3 = OFF_P1 + 2*512;          // [2*9][512]
static constexpr size_t OFF_P5 = OFF_P3 + 18*512;         // [2*25][512]
static constexpr size_t OFF_G0 = OFF_P5 + 50*512;         // [2*1][64]
static constexpr size_t OFF_G1 = OFF_G0 + 2*64;           // [2*9][64]
static constexpr size_t OFF_G2 = OFF_G1 + 18*64;          // [2*25][64]
static constexpr size_t OFF_S  = OFF_G2 + 50*64;          // [2][64][2304] f32
static constexpr size_t OFF_Q  = OFF_S  + 294912;         // [2][8][2304] f32
static constexpr size_t OFF_K  = OFF_Q  + 36864;          // [2][8][2304] f32
static constexpr size_t OFF_V  = OFF_K  + 36864;          // bf16 [2][64][2304]
static constexpr size_t OFF_SAP= OFF_V  + 294912;         // [4][2][64][2304] PV partials
static constexpr size_t OFF_SA = OFF_SAP+ 4*294912;       // [2][64][2304] f32
static constexpr size_t OFF_GC = OFF_SA + 294912;         // [3][2][64][2304] f32
static constexpr size_t OFF_MEAN = OFF_GC + 3*294912;     // [2][64] SA-mean only
static constexpr size_t OFF_WGT  = OFF_MEAN + 512;        // [2][4][64]
static constexpr size_t OFF_FUSED= OFF_WGT + 512;         // (unused)
static constexpr size_t OFF_Y0 = OFF_FUSED + 1179648;     // [2][256][2304]
static constexpr size_t OFF_Y1 = OFF_Y0 + 1179648;        // [2][128][2304]
static constexpr size_t OFF_Y2 = OFF_Y1 + 589824;         // [2][64][2304]
static constexpr size_t OFF_Y3 = OFF_Y2 + 294912;         // [2][64][2304]
static constexpr size_t OFF_PA = OFF_Y3 + 294912;         // bf16 [2][2304][2304]

// ---------------- K1: adaptive pools (1,3,5) ----------------
__global__ __launch_bounds__(256) void k_pool(const float* __restrict__ x, float* __restrict__ wsp){
  __shared__ float pl[2304];
  __shared__ float red[4];
  int bc = blockIdx.x;            // b*512 + cin
  int b = bc >> 9, cin = bc & 511;
  const float* src = x + (size_t)bc * 2304;
  int t = threadIdx.x;
  float ls = 0.f;
  #pragma unroll
  for (int j = 0; j < 9; j++){ int i = t + j*256; float v = src[i]; pl[i] = v; ls += v; }
  #pragma unroll
  for (int o = 32; o; o >>= 1) ls += __shfl_xor(ls, o);
  if ((t & 63) == 0) red[t >> 6] = ls;
  __syncthreads();
  if (t == 0) wsp[OFF_P1 + (size_t)b*512 + cin] = (red[0]+red[1]+red[2]+red[3]) * (1.f/2304.f);
  if (t < 9){
    int ry = t/3, rx = t%3; float sm = 0.f;
    for (int yy = 0; yy < 16; yy++)
      for (int xx = 0; xx < 16; xx++) sm += pl[(ry*16+yy)*48 + rx*16+xx];
    wsp[OFF_P3 + ((size_t)b*9 + t)*512 + cin] = sm * (1.f/256.f);
  } else if (t < 34){
    int j = t - 9; int ry = j/5, rx = j%5;
    int hs = (ry*48)/5, he = ((ry+1)*48+4)/5, cs = (rx*48)/5, ce = ((rx+1)*48+4)/5;
    float sm = 0.f;
    for (int yy = hs; yy < he; yy++)
      for (int xx = cs; xx < ce; xx++) sm += pl[yy*48+xx];
    wsp[OFF_P5 + ((size_t)b*25 + j)*512 + cin] = sm / (float)((he-hs)*(ce-cs));
  }
}

// ---------------- K2: tiny 64x512 convs on pooled cols ----------------
__global__ __launch_bounds__(256) void k_gcconv(
    const float* __restrict__ w0, const float* __restrict__ b0,
    const float* __restrict__ w1, const float* __restrict__ b1,
    const float* __restrict__ w2, const float* __restrict__ b2,
    float* __restrict__ wsp){
  int col = blockIdx.x;          // 0..69
  const float* w; const float* bias; const float* pool; float* dst;
  if (col < 2){ w = w0; bias = b0; pool = wsp + OFF_P1 + (size_t)col*512; dst = wsp + OFF_G0 + (size_t)col*64; }
  else if (col < 20){ int c = col-2;  w = w1; bias = b1; pool = wsp + OFF_P3 + (size_t)c*512; dst = wsp + OFF_G1 + (size_t)c*64; }
  else              { int c = col-20; w = w2; bias = b2; pool = wsp + OFF_P5 + (size_t)c*512; dst = wsp + OFF_G2 + (size_t)c*64; }
  int t = threadIdx.x; int r = t >> 2, qd = t & 3;
  const float* wr = w + (size_t)r*512 + qd*128;
  const float* pr = pool + qd*128;
  float acc = 0.f;
  #pragma unroll 8
  for (int k = 0; k < 128; k += 4){
    float4 wv = *(const float4*)(wr + k); float4 pv = *(const float4*)(pr + k);
    acc += wv.x*pv.x + wv.y*pv.y + wv.z*pv.z + wv.w*pv.w;
  }
  acc += __shfl_xor(acc, 1); acc += __shfl_xor(acc, 2);
  if (qd == 0) dst[r] = fmaxf(acc + bias[r], 0.f);
}

// ---------------- K3: s = relu(Wgc3.x+b) [64x512x4608] + fused QKV epilogue ----------------
// grid 144: b = blk/72, 32-col tile. Block holds full S-tile [64][32] in LDS -> QKV.
__global__ __launch_bounds__(256) void k_sgemm_qkv(const float* __restrict__ x,
    const float* __restrict__ w, const float* __restrict__ bias,
    const float* __restrict__ wq, const float* __restrict__ bq,
    const float* __restrict__ wk, const float* __restrict__ bk,
    const float* __restrict__ wv, const float* __restrict__ bv,
    float* __restrict__ wsp){
  __shared__ __align__(16) float wt[64][66];     // [k][row]
  __shared__ __align__(16) float s_lds[64][36];  // [chan][col]
  __shared__ float wq_lds[80][64];
  __shared__ float bqkv[80];
  int cb = blockIdx.x;
  int b = cb / 72, hw0 = (cb - b*72)*32;
  int tid = threadIdx.x;
  // stage qkv weights (80x64) + biases
  for (int i = tid; i < 5120; i += 256){
    int row = i >> 6, k = i & 63;
    wq_lds[row][k] = (row < 8) ? wq[(size_t)row*64 + k]
                   : (row < 16) ? wk[(size_t)(row-8)*64 + k]
                                : wv[(size_t)(row-16)*64 + k];
  }
  if (tid < 80) bqkv[tid] = (tid < 8) ? bq[tid] : (tid < 16) ? bk[tid-8] : bv[tid-16];
  int sr = tid >> 2, sseg = tid & 3;
  int cc0 = (tid & 7)*4, r0 = (tid >> 3)*2;
  const float* xb = x + (size_t)b*512*2304 + hw0 + cc0;
  float acc[2][4] = {};
  for (int kc = 0; kc < 512; kc += 64){
    __syncthreads();
    #pragma unroll
    for (int i = 0; i < 16; i += 4){
      float4 v = *(const float4*)(w + (size_t)sr*512 + kc + sseg*16 + i);
      wt[sseg*16+i+0][sr]=v.x; wt[sseg*16+i+1][sr]=v.y;
      wt[sseg*16+i+2][sr]=v.z; wt[sseg*16+i+3][sr]=v.w;
    }
    __syncthreads();
    const float* xk = xb + (size_t)kc*2304;
    #pragma unroll 4
    for (int k = 0; k < 64; k++){
      float2 wv2 = *(const float2*)&wt[k][r0];
      float4 xv = *(const float4*)(xk + (size_t)k*2304);
      acc[0][0]+=wv2.x*xv.x; acc[0][1]+=wv2.x*xv.y; acc[0][2]+=wv2.x*xv.z; acc[0][3]+=wv2.x*xv.w;
      acc[1][0]+=wv2.y*xv.x; acc[1][1]+=wv2.y*xv.y; acc[1][2]+=wv2.y*xv.z; acc[1][3]+=wv2.y*xv.w;
    }
  }
  #pragma unroll
  for (int i = 0; i < 2; i++){
    float bi = bias[r0+i];
    float4 o;
    o.x = fmaxf(acc[i][0]+bi, 0.f); o.y = fmaxf(acc[i][1]+bi, 0.f);
    o.z = fmaxf(acc[i][2]+bi, 0.f); o.w = fmaxf(acc[i][3]+bi, 0.f);
    *(float4*)(wsp + OFF_S + ((size_t)b*64 + r0+i)*2304 + hw0 + cc0) = o;
    *(float4*)&s_lds[r0+i][cc0] = o;
  }
  __syncthreads();
  // QKV: 80 rows x 32 cols
  int col = tid & 31, rgrp = tid >> 5;
  float a2[10];
  #pragma unroll
  for (int i = 0; i < 10; i++) a2[i] = bqkv[rgrp*10 + i];
  for (int k = 0; k < 64; k++){
    float sv = s_lds[k][col];
    #pragma unroll
    for (int i = 0; i < 10; i++) a2[i] += wq_lds[rgrp*10 + i][k]*sv;
  }
  __hip_bfloat16* Vb = reinterpret_cast<__hip_bfloat16*>(wsp + OFF_V);
  int hw = hw0 + col;
  #pragma unroll
  for (int i = 0; i < 10; i++){
    int r = rgrp*10 + i;
    if (r < 8)       wsp[OFF_Q + (size_t)b*18432 + (size_t)r*2304 + hw] = a2[i];
    else if (r < 16) wsp[OFF_K + (size_t)b*18432 + (size_t)(r-8)*2304 + hw] = a2[i];
    else             Vb[(size_t)b*147456 + (size_t)(r-16)*2304 + hw] = __float2bfloat16(a2[i]);
  }
}

// ---------------- K5: attention logits + softmax -> P (bf16), 8 rows/block ----------------
__global__ __launch_bounds__(256) void k_softmax(float* __restrict__ wsp){
  int blk = blockIdx.x;           // 576
  int row0 = blk * 8;
  int b = row0 / 2304, m0 = row0 - b*2304;
  const float* kk = wsp + OFF_K + (size_t)b*18432;
  __shared__ float qs[8][9];
  __shared__ float redm[4][8], reds[4][8];
  int t = threadIdx.x;
  if (t < 64) qs[t>>3][t&7] = wsp[OFF_Q + (size_t)b*18432 + (size_t)(t&7)*2304 + m0 + (t>>3)];
  __syncthreads();
  float l[9][8];
  #pragma unroll
  for (int j = 0; j < 9; j++){
    int n = t + j*256;
    float k8[8];
    #pragma unroll
    for (int c = 0; c < 8; c++) k8[c] = kk[(size_t)c*2304 + n];
    #pragma unroll
    for (int m = 0; m < 8; m++){
      float a = 0.f;
      #pragma unroll
      for (int c = 0; c < 8; c++) a += qs[m][c]*k8[c];
      l[j][m] = a;
    }
  }
  int w = t >> 6, lane = t & 63;
  #pragma unroll
  for (int m = 0; m < 8; m++){
    float v = l[0][m];
    #pragma unroll
    for (int j = 1; j < 9; j++) v = fmaxf(v, l[j][m]);
    #pragma unroll
    for (int o = 32; o; o >>= 1) v = fmaxf(v, __shfl_xor(v, o));
    if (lane == 0) redm[w][m] = v;
  }
  __syncthreads();
  float Mm[8];
  #pragma unroll
  for (int m = 0; m < 8; m++)
    Mm[m] = fmaxf(fmaxf(redm[0][m], redm[1][m]), fmaxf(redm[2][m], redm[3][m]));
  #pragma unroll
  for (int m = 0; m < 8; m++){
    float s = 0.f;
    #pragma unroll
    for (int j = 0; j < 9; j++){ l[j][m] = __expf(l[j][m]-Mm[m]); s += l[j][m]; }
    #pragma unroll
    for (int o = 32; o; o >>= 1) s += __shfl_xor(s, o);
    if (lane == 0) reds[w][m] = s;
  }
  __syncthreads();
  __hip_bfloat16* Pp = reinterpret_cast<__hip_bfloat16*>(wsp + OFF_PA);
  #pragma unroll
  for (int m = 0; m < 8; m++){
    float inv = 1.f / (reds[0][m]+reds[1][m]+reds[2][m]+reds[3][m]);
    #pragma unroll
    for (int j = 0; j < 9; j++){
      int n = t + j*256;
      Pp[(size_t)(b*2304 + m0 + m)*2304 + n] = __float2bfloat16(l[j][m]*inv);
    }
  }
}

// ---------------- K6: PV partials via MFMA bf16, n-split 4 ----------------
__global__ __launch_bounds__(256) void k_pv(float* __restrict__ wsp){
  int mb = blockIdx.x * 16;      // 144 m-tiles
  int b  = blockIdx.y;
  int ns = blockIdx.z;           // 4 n-quarters
  int t = threadIdx.x;
  int w = t >> 6, lane = t & 63;
  int arow = lane & 15, kg = lane >> 4;
  const short* P = (const short*)(wsp + OFF_PA) + (size_t)(b*2304 + mb + arow)*2304 + kg*8;
  const short* V = (const short*)(wsp + OFF_V) + (size_t)b*147456 + (size_t)(w*16 + arow)*2304 + kg*8;
  f32x4 acc = {0.f, 0.f, 0.f, 0.f};
  int n0 = ns*576;
  for (int nb = n0; nb < n0 + 576; nb += 32){
    short8 a  = *(const short8*)(P + nb);
    short8 bf = *(const short8*)(V + nb);
    acc = __builtin_amdgcn_mfma_f32_16x16x32_bf16(a, bf, acc, 0, 0, 0);
  }
  __shared__ float tile[16][68];
  #pragma unroll
  for (int r = 0; r < 4; r++) tile[kg*4 + r][w*16 + arow] = acc[r];
  __syncthreads();
  int c = t >> 2, mq = t & 3;
  float4 o;
  o.x = tile[mq*4+0][c]; o.y = tile[mq*4+1][c];
  o.z = tile[mq*4+2][c]; o.w = tile[mq*4+3][c];
  *(float4*)(wsp + OFF_SAP + (size_t)ns*294912 + ((size_t)b*64 + c)*2304 + mb + mq*4) = o;
}

// ---------------- K7: sa = gamma * sum(partials) + s ----------------
__global__ __launch_bounds__(256) void k_sacomb(float* __restrict__ wsp, const float* __restrict__ gamma){
  size_t i = (size_t)blockIdx.x*256 + threadIdx.x;   // 294912 elems
  float g = gamma[0];
  float p = wsp[OFF_SAP + i] + wsp[OFF_SAP + 294912 + i]
          + wsp[OFF_SAP + 2*294912 + i] + wsp[OFF_SAP + 3*294912 + i];
  wsp[OFF_SA + i] = g*p + wsp[OFF_S + i];
}

// ---------------- K8: bilinear upsample gc branches (align_corners=True) ----------------
__global__ __launch_bounds__(256) void k_gcup(float* __restrict__ wsp){
  int px = blockIdx.x*256 + threadIdx.x;   // 0..2303
  int pb = blockIdx.y;                     // t*128 + b*64 + c
  int c = pb & 63, b = (pb >> 6) & 1, t = pb >> 7;
  int oy = px / 48, ox = px - oy*48;
  int ps; const float* g;
  if (t == 0){ ps = 1; g = wsp + OFF_G0 + (size_t)b*64; }
  else if (t == 1){ ps = 3; g = wsp + OFF_G1 + (size_t)b*9*64; }
  else { ps = 5; g = wsp + OFF_G2 + (size_t)b*25*64; }
  float scale = (ps - 1) / 47.f;
  float cy = oy*scale, cx = ox*scale;
  int y0 = (int)cy, x0 = (int)cx;
  float wy = cy - y0, wx = cx - x0;
  int y1 = min(y0+1, ps-1), x1 = min(x0+1, ps-1);
  float a  = g[(y0*ps+x0)*64 + c], bq = g[(y0*ps+x1)*64 + c];
  float cc = g[(y1*ps+x0)*64 + c], d  = g[(y1*ps+x1)*64 + c];
  float v = (a*(1.f-wx) + bq*wx)*(1.f-wy) + (cc*(1.f-wx) + d*wx)*wy;
  wsp[OFF_GC + (((size_t)t*2 + b)*64 + c)*2304 + px] = v;
}

// ---------------- K9: spatial mean of SA only ----------------
__global__ __launch_bounds__(256) void k_gap(float* __restrict__ wsp){
  __shared__ float red[4];
  int blk = blockIdx.x; int c = blk & 63, b = blk >> 6;   // 128 blocks
  const float* src = wsp + OFF_SA + ((size_t)b*64 + c)*2304;
  float s = 0.f;
  for (int i = threadIdx.x; i < 2304; i += 256) s += src[i];
  #pragma unroll
  for (int o = 32; o; o >>= 1) s += __shfl_xor(s, o);
  if ((threadIdx.x & 63) == 0) red[threadIdx.x >> 6] = s;
  __syncthreads();
  if (threadIdx.x == 0)
    wsp[OFF_MEAN + (size_t)b*64 + c] = (red[0]+red[1]+red[2]+red[3]) * (1.f/2304.f);
}

// ---------------- K10: SE (gc means computed analytically from G) ----------------
__global__ __launch_bounds__(256) void k_se(
    const float* __restrict__ w_se1, const float* __restrict__ w_se2,
    const float* __restrict__ w_se3, const float* __restrict__ w_se4,
    float* __restrict__ wsp){
  int b = blockIdx.x; int tid = threadIdx.x;
  int g = tid >> 6, c = tid & 63;
  __shared__ float mean_lds[4][64];
  float mv;
  if (g == 0){                       // slot0: mean(SA)
    mv = wsp[OFF_MEAN + (size_t)b*64 + c];
  } else if (g == 3){                // slot3: mean(gc0) = G0 (constant image)
    mv = wsp[OFF_G0 + (size_t)b*64 + c];
  } else if (g == 2){                // slot2: mean(gc1), ps=3
    float w3[3] = {0.f,0.f,0.f};
    for (int o = 0; o < 48; o++){
      float cc = o*(2.f/47.f); int i0 = (int)cc; float f = cc - i0;
      int i1 = min(i0+1, 2);
      w3[i0] += 1.f - f; w3[i1] += f;
    }
    float s = 0.f;
    for (int sy = 0; sy < 3; sy++)
      for (int sx = 0; sx < 3; sx++)
        s += w3[sy]*w3[sx]*wsp[OFF_G1 + ((size_t)b*9 + sy*3 + sx)*64 + c];
    mv = s * (1.f/(48.f*48.f));
  } else {                           // slot1: mean(gc2), ps=5
    float w5[5] = {0.f,0.f,0.f,0.f,0.f};
    for (int o = 0; o < 48; o++){
      float cc = o*(4.f/47.f); int i0 = (int)cc; float f = cc - i0;
      int i1 = min(i0+1, 4);
      w5[i0] += 1.f - f; w5[i1] += f;
    }
    float s = 0.f;
    for (int sy = 0; sy < 5; sy++)
      for (int sx = 0; sx < 5; sx++)
        s += w5[sy]*w5[sx]*wsp[OFF_G2 + ((size_t)b*25 + sy*5 + sx)*64 + c];
    mv = s * (1.f/(48.f*48.f));
  }
  mean_lds[g][c] = mv;
  __syncthreads();
  const float* w = (g == 0) ? w_se1 : (g == 1) ? w_se2 : (g == 2) ? w_se3 : w_se4;
  float acc = 0.f;
  for (int j = 0; j < 64; j++) acc += w[(size_t)c*64 + j]*mean_lds[g][j];
  float sg = 1.f / (1.f + __expf(-acc));
  __shared__ float sh[4][64];
  sh[g][c] = sg;
  __syncthreads();
  float a0 = sh[0][c], a1 = sh[1][c], a2 = sh[2][c], a3 = sh[3][c];
  float mxv = fmaxf(fmaxf(a0, a1), fmaxf(a2, a3));
  float e = __expf(sg - mxv);
  float sum = __expf(a0-mxv) + __expf(a1-mxv) + __expf(a2-mxv) + __expf(a3-mxv);
  wsp[OFF_WGT + ((size_t)b*4 + g)*64 + c] = e / sum;
}

// ---------------- K12: out-head GEMMs, wgt folded into weight staging ----------------
__global__ __launch_bounds__(256) void k_outgemm(
    const float* __restrict__ w0, const float* __restrict__ b0,
    const float* __restrict__ w1, const float* __restrict__ b1,
    const float* __restrict__ w2, const float* __restrict__ b2,
    const float* __restrict__ w3, const float* __restrict__ b3,
    float* __restrict__ wsp){
  __shared__ __align__(16) float wt[64][68];
  __shared__ float wg[256];
  int cb = blockIdx.x, rb = blockIdx.y;
  int b = cb / 36, hw0 = (cb - b*36)*64;
  const float* wsrc; const float* bsrc; size_t dstoff; int dstC; int row0;
  if (rb < 4){ wsrc = w0 + (size_t)rb*64*256; bsrc = b0 + rb*64; dstoff = OFF_Y0; dstC = 256; row0 = rb*64; }
  else if (rb < 6){ wsrc = w1 + (size_t)(rb-4)*64*256; bsrc = b1 + (rb-4)*64; dstoff = OFF_Y1; dstC = 128; row0 = (rb-4)*64; }
  else if (rb == 6){ wsrc = w2; bsrc = b2; dstoff = OFF_Y2; dstC = 64; row0 = 0; }
  else { wsrc = w3; bsrc = b3; dstoff = OFF_Y3; dstC = 64; row0 = 0; }
  int tid = threadIdx.x;
  wg[tid] = wsp[OFF_WGT + (size_t)b*256 + tid];
  int sr = tid >> 2, sseg = tid & 3;
  int cc0 = (tid & 15)*4, r0 = (tid >> 4)*4;
  float acc[4][4] = {};
  for (int kc = 0; kc < 256; kc += 64){
    __syncthreads();
    #pragma unroll
    for (int i = 0; i < 16; i += 4){
      float4 v = *(const float4*)(wsrc + (size_t)sr*256 + kc + sseg*16 + i);
      int kl = sseg*16 + i;
      wt[kl+0][sr]=v.x*wg[kc+kl+0]; wt[kl+1][sr]=v.y*wg[kc+kl+1];
      wt[kl+2][sr]=v.z*wg[kc+kl+2]; wt[kl+3][sr]=v.w*wg[kc+kl+3];
    }
    __syncthreads();
    int gidx = kc >> 6;
    size_t srcbase = (gidx < 3) ? OFF_GC + ((size_t)(gidx*2 + b))*147456
                                : OFF_SA + (size_t)b*147456;
    const float* fk = wsp + srcbase + hw0 + cc0;
    #pragma unroll 4
    for (int k = 0; k < 64; k++){
      float4 wv = *(const float4*)&wt[k][r0];
      float4 xv = *(const float4*)(fk + (size_t)k*2304);
      acc[0][0]+=wv.x*xv.x; acc[0][1]+=wv.x*xv.y; acc[0][2]+=wv.x*xv.z; acc[0][3]+=wv.x*xv.w;
      acc[1][0]+=wv.y*xv.x; acc[1][1]+=wv.y*xv.y; acc[1][2]+=wv.y*xv.z; acc[1][3]+=wv.y*xv.w;
      acc[2][0]+=wv.z*xv.x; acc[2][1]+=wv.z*xv.y; acc[2][2]+=wv.z*xv.z; acc[2][3]+=wv.z*xv.w;
      acc[3][0]+=wv.w*xv.x; acc[3][1]+=wv.w*xv.y; acc[3][2]+=wv.w*xv.z; acc[3][3]+=wv.w*xv.w;
    }
  }
  #pragma unroll
  for (int i = 0; i < 4; i++){
    float bi = bsrc[r0+i];
    float4 o;
    o.x = fmaxf(acc[i][0]+bi, 0.f); o.y = fmaxf(acc[i][1]+bi, 0.f);
    o.z = fmaxf(acc[i][2]+bi, 0.f); o.w = fmaxf(acc[i][3]+bi, 0.f);
    *(float4*)(wsp + dstoff + ((size_t)b*dstC + row0 + r0 + i)*2304 + hw0 + cc0) = o;
  }
}

// ---------------- K13: all 4 upsample heads in one kernel ----------------
template<int SC>
__device__ __forceinline__ void up_one(int idx, const float* __restrict__ src, float* __restrict__ dst){
  constexpr int OW = 48*SC, OH = 48*SC;
  constexpr int WQ = OW/4;
  int q = idx % WQ; int rest = idx / WQ;
  int oy = rest % OH; int pc = rest / OH;
  const float* sp = src + (size_t)pc * 2304;
  float cy = fminf(fmaxf((oy + 0.5f)*(1.0f/SC) - 0.5f, 0.f), 47.f);
  int y0 = (int)cy;
  float wy = cy - y0;
  int y1 = min(y0+1, 47);
  const float* r0 = sp + y0*48; const float* r1 = sp + y1*48;
  float outv[4];
  #pragma unroll
  for (int i = 0; i < 4; i++){
    int ox = q*4 + i;
    float cx = fminf(fmaxf((ox + 0.5f)*(1.0f/SC) - 0.5f, 0.f), 47.f);
    int x0 = (int)cx; float wx = cx - x0; int x1 = min(x0+1, 47);
    float a  = r0[x0]*(1.f-wx) + r0[x1]*wx;
    float bq = r1[x0]*(1.f-wx) + r1[x1]*wx;
    outv[i] = a*(1.f-wy) + bq*wy;
  }
  float4 o; o.x = outv[0]; o.y = outv[1]; o.z = outv[2]; o.w = outv[3];
  *(float4*)(dst + (size_t)pc*OH*OW + (size_t)oy*OW + q*4) = o;
}

__global__ __launch_bounds__(256) void k_upsample_all(const float* __restrict__ wsp, float* __restrict__ out){
  int t = blockIdx.x*256 + threadIdx.x;
  if (t < 1179648)       up_one<2>(t,           wsp + OFF_Y0, out);
  else if (t < 3538944)  up_one<4>(t - 1179648, wsp + OFF_Y1, out + 4718592);
  else if (t < 8257536)  up_one<8>(t - 3538944, wsp + OFF_Y2, out + 14155776);
  else                   up_one<16>(t - 8257536, wsp + OFF_Y3, out + 33030144);
}

// ---------------- launcher ----------------
extern "C" void kernel_launch(void* const* d_in, const int* in_sizes, int n_in,
                              void* d_out, int out_size, void* d_ws, size_t ws_size,
                              hipStream_t stream){
  const float* x     = (const float*)d_in[0];
  const float* w_gc0 = (const float*)d_in[1];
  const float* b_gc0 = (const float*)d_in[2];
  const float* w_gc1 = (const float*)d_in[3];
  const float* b_gc1 = (const float*)d_in[4];
  const float* w_gc2 = (const float*)d_in[5];
  const float* b_gc2 = (const float*)d_in[6];
  const float* w_gc3 = (const float*)d_in[7];
  const float* b_gc3 = (const float*)d_in[8];
  const float* w_q   = (const float*)d_in[9];
  const float* b_q   = (const float*)d_in[10];
  const float* w_k   = (const float*)d_in[11];
  const float* b_k   = (const float*)d_in[12];
  const float* w_v   = (const float*)d_in[13];
  const float* b_v   = (const float*)d_in[14];
  const float* gamma = (const float*)d_in[15];
  const float* w_se1 = (const float*)d_in[16];
  const float* w_se2 = (const float*)d_in[17];
  const float* w_se3 = (const float*)d_in[18];
  const float* w_se4 = (const float*)d_in[19];
  const float* w_out0 = (const float*)d_in[20];
  const float* b_out0 = (const float*)d_in[21];
  const float* w_out1 = (const float*)d_in[22];
  const float* b_out1 = (const float*)d_in[23];
  const float* w_out2 = (const float*)d_in[24];
  const float* b_out2 = (const float*)d_in[25];
  const float* w_out3 = (const float*)d_in[26];
  const float* b_out3 = (const float*)d_in[27];
  float* wsp = (float*)d_ws;
  float* out = (float*)d_out;

  k_pool     <<<1024, 256, 0, stream>>>(x, wsp);
  k_gcconv   <<<70,   256, 0, stream>>>(w_gc0,b_gc0,w_gc1,b_gc1,w_gc2,b_gc2, wsp);
  k_sgemm_qkv<<<144,  256, 0, stream>>>(x, w_gc3, b_gc3, w_q,b_q,w_k,b_k,w_v,b_v, wsp);
  k_softmax  <<<576,  256, 0, stream>>>(wsp);
  k_pv       <<<dim3(144,2,4), 256, 0, stream>>>(wsp);
  k_sacomb   <<<1152, 256, 0, stream>>>(wsp, gamma);
  k_gcup     <<<dim3(9,384), 256, 0, stream>>>(wsp);
  k_gap      <<<128,  256, 0, stream>>>(wsp);
  k_se       <<<2,    256, 0, stream>>>(w_se1,w_se2,w_se3,w_se4, wsp);
  k_outgemm  <<<dim3(72,8), 256, 0, stream>>>(w_out0,b_out0,w_out1,b_out1,w_out2,b_out2,w_out3,b_out3, wsp);
  k_upsample_all<<<105984, 256, 0, stream>>>(wsp, out);
}

// Round 4
// 229.746 us; speedup vs baseline: 1.3420x; 1.1904x over previous
//
#include <hip/hip_runtime.h>
#include <hip/hip_bf16.h>
#include <hip/hip_fp16.h>

// B=2, Cin=512, C=64, H=W=48, N=2304 spatial, 4608 total columns.

typedef __attribute__((ext_vector_type(8))) short short8;
typedef __attribute__((ext_vector_type(4))) float f32x4;

#define GLOAD_LDS(gsrc, ldst) \
  __builtin_amdgcn_global_load_lds((const __attribute__((address_space(1))) void*)(gsrc), \
                                   (__attribute__((address_space(3))) void*)(ldst), 16, 0, 0)

// ---------------- ws layout (float offsets) ----------------
static constexpr size_t OFF_P1 = 0;                       // [2][512]
static constexpr size_t OFF_P3 = OFF_P1 + 2*512;          // [2*9][512]
static constexpr size_t OFF_P5 = OFF_P3 + 18*512;         // [2*25][512]
static constexpr size_t OFF_G0 = OFF_P5 + 50*512;         // [2*1][64]
static constexpr size_t OFF_G1 = OFF_G0 + 2*64;           // [2*9][64]
static constexpr size_t OFF_G2 = OFF_G1 + 18*64;          // [2*25][64]
static constexpr size_t OFF_S  = OFF_G2 + 50*64;          // [2][64][2304] f32
static constexpr size_t OFF_Q  = OFF_S  + 294912;         // [2][8][2304] f32
static constexpr size_t OFF_K  = OFF_Q  + 36864;          // [2][8][2304] f32
static constexpr size_t OFF_V  = OFF_K  + 36864;          // bf16 [2][64][2304]
static constexpr size_t OFF_SAP= OFF_V  + 294912;         // (unused)
static constexpr size_t OFF_SA = OFF_SAP+ 4*294912;       // [2][64][2304] f32
static constexpr size_t OFF_GC = OFF_SA + 294912;         // [3][2][64][2304] f32
static constexpr size_t OFF_MEAN = OFF_GC + 3*294912;     // [2][64]
static constexpr size_t OFF_WGT  = OFF_MEAN + 512;        // [2][4][64]
static constexpr size_t OFF_FUSED= OFF_WGT + 512;         // (unused)
static constexpr size_t OFF_Y0 = OFF_FUSED + 1179648;     // [2][256][2304]
static constexpr size_t OFF_Y1 = OFF_Y0 + 1179648;        // [2][128][2304]
static constexpr size_t OFF_Y2 = OFF_Y1 + 589824;         // [2][64][2304]
static constexpr size_t OFF_Y3 = OFF_Y2 + 294912;         // [2][64][2304]
static constexpr size_t OFF_PA = OFF_Y3 + 294912;         // (unused now)

// ---------------- K1: adaptive pools (1,3,5) ----------------
__global__ __launch_bounds__(256) void k_pool(const float* __restrict__ x, float* __restrict__ wsp){
  __shared__ float pl[2304];
  __shared__ float red[4];
  int bc = blockIdx.x;            // b*512 + cin
  int b = bc >> 9, cin = bc & 511;
  const float* src = x + (size_t)bc * 2304;
  int t = threadIdx.x;
  float ls = 0.f;
  #pragma unroll
  for (int j = 0; j < 9; j++){ int i = t + j*256; float v = src[i]; pl[i] = v; ls += v; }
  #pragma unroll
  for (int o = 32; o; o >>= 1) ls += __shfl_xor(ls, o);
  if ((t & 63) == 0) red[t >> 6] = ls;
  __syncthreads();
  if (t == 0) wsp[OFF_P1 + (size_t)b*512 + cin] = (red[0]+red[1]+red[2]+red[3]) * (1.f/2304.f);
  if (t < 9){
    int ry = t/3, rx = t%3; float sm = 0.f;
    for (int yy = 0; yy < 16; yy++)
      for (int xx = 0; xx < 16; xx++) sm += pl[(ry*16+yy)*48 + rx*16+xx];
    wsp[OFF_P3 + ((size_t)b*9 + t)*512 + cin] = sm * (1.f/256.f);
  } else if (t < 34){
    int j = t - 9; int ry = j/5, rx = j%5;
    int hs = (ry*48)/5, he = ((ry+1)*48+4)/5, cs = (rx*48)/5, ce = ((rx+1)*48+4)/5;
    float sm = 0.f;
    for (int yy = hs; yy < he; yy++)
      for (int xx = cs; xx < ce; xx++) sm += pl[yy*48+xx];
    wsp[OFF_P5 + ((size_t)b*25 + j)*512 + cin] = sm / (float)((he-hs)*(ce-cs));
  }
}

// ---------------- K2: tiny 64x512 convs on pooled cols ----------------
__global__ __launch_bounds__(256) void k_gcconv(
    const float* __restrict__ w0, const float* __restrict__ b0,
    const float* __restrict__ w1, const float* __restrict__ b1,
    const float* __restrict__ w2, const float* __restrict__ b2,
    float* __restrict__ wsp){
  int col = blockIdx.x;          // 0..69
  const float* w; const float* bias; const float* pool; float* dst;
  if (col < 2){ w = w0; bias = b0; pool = wsp + OFF_P1 + (size_t)col*512; dst = wsp + OFF_G0 + (size_t)col*64; }
  else if (col < 20){ int c = col-2;  w = w1; bias = b1; pool = wsp + OFF_P3 + (size_t)c*512; dst = wsp + OFF_G1 + (size_t)c*64; }
  else              { int c = col-20; w = w2; bias = b2; pool = wsp + OFF_P5 + (size_t)c*512; dst = wsp + OFF_G2 + (size_t)c*64; }
  int t = threadIdx.x; int r = t >> 2, qd = t & 3;
  const float* wr = w + (size_t)r*512 + qd*128;
  const float* pr = pool + qd*128;
  float acc = 0.f;
  #pragma unroll 8
  for (int k = 0; k < 128; k += 4){
    float4 wv = *(const float4*)(wr + k); float4 pv = *(const float4*)(pr + k);
    acc += wv.x*pv.x + wv.y*pv.y + wv.z*pv.z + wv.w*pv.w;
  }
  acc += __shfl_xor(acc, 1); acc += __shfl_xor(acc, 2);
  if (qd == 0) dst[r] = fmaxf(acc + bias[r], 0.f);
}

// ---------------- K3: s = relu(Wgc3.x+b) + fused QKV, X staged via global_load_lds ----------------
__global__ __launch_bounds__(256) void k_sgemm_qkv(const float* __restrict__ x,
    const float* __restrict__ w, const float* __restrict__ bias,
    const float* __restrict__ wq, const float* __restrict__ bq,
    const float* __restrict__ wk, const float* __restrict__ bk,
    const float* __restrict__ wv, const float* __restrict__ bv,
    float* __restrict__ wsp){
  __shared__ __align__(16) float wt[64][66];     // [k][row]
  __shared__ __align__(16) float xs[64][32];     // [k][col] staged X chunk (8 KB, linear for dma)
  __shared__ __align__(16) float s_lds[64][36];  // [chan][col]
  __shared__ float wq_lds[80][64];
  __shared__ float bqkv[80];
  int cb = blockIdx.x;
  int b = cb / 72, hw0 = (cb - b*72)*32;
  int tid = threadIdx.x;
  int wv_ = tid >> 6, lane = tid & 63;
  for (int i = tid; i < 5120; i += 256){
    int row = i >> 6, k = i & 63;
    wq_lds[row][k] = (row < 8) ? wq[(size_t)row*64 + k]
                   : (row < 16) ? wk[(size_t)(row-8)*64 + k]
                                : wv[(size_t)(row-16)*64 + k];
  }
  if (tid < 80) bqkv[tid] = (tid < 8) ? bq[tid] : (tid < 16) ? bk[tid-8] : bv[tid-16];
  int sr = tid >> 2, sseg = tid & 3;
  int cc0 = (tid & 7)*4, r0 = (tid >> 3)*2;
  const float* xb = x + (size_t)b*512*2304 + hw0;
  float acc[2][4] = {};
  for (int kc = 0; kc < 512; kc += 64){
    __syncthreads();
    // X dma: wave wv_ stages rows wv_*16 .. +15 (2 issues of 1024B)
    {
      int rr0 = wv_*16 + (lane >> 3);
      const float* g0 = xb + (size_t)(kc + rr0)*2304 + (lane & 7)*4;
      const float* g1 = xb + (size_t)(kc + rr0 + 8)*2304 + (lane & 7)*4;
      GLOAD_LDS(g0, &xs[wv_*16][0]);
      GLOAD_LDS(g1, &xs[wv_*16 + 8][0]);
    }
    #pragma unroll
    for (int i = 0; i < 16; i += 4){
      float4 v = *(const float4*)(w + (size_t)sr*512 + kc + sseg*16 + i);
      wt[sseg*16+i+0][sr]=v.x; wt[sseg*16+i+1][sr]=v.y;
      wt[sseg*16+i+2][sr]=v.z; wt[sseg*16+i+3][sr]=v.w;
    }
    __syncthreads();
    #pragma unroll 4
    for (int k = 0; k < 64; k++){
      float2 wv2 = *(const float2*)&wt[k][r0];
      float4 xv = *(const float4*)&xs[k][cc0];
      acc[0][0]+=wv2.x*xv.x; acc[0][1]+=wv2.x*xv.y; acc[0][2]+=wv2.x*xv.z; acc[0][3]+=wv2.x*xv.w;
      acc[1][0]+=wv2.y*xv.x; acc[1][1]+=wv2.y*xv.y; acc[1][2]+=wv2.y*xv.z; acc[1][3]+=wv2.y*xv.w;
    }
  }
  #pragma unroll
  for (int i = 0; i < 2; i++){
    float bi = bias[r0+i];
    float4 o;
    o.x = fmaxf(acc[i][0]+bi, 0.f); o.y = fmaxf(acc[i][1]+bi, 0.f);
    o.z = fmaxf(acc[i][2]+bi, 0.f); o.w = fmaxf(acc[i][3]+bi, 0.f);
    *(float4*)(wsp + OFF_S + ((size_t)b*64 + r0+i)*2304 + hw0 + cc0) = o;
    *(float4*)&s_lds[r0+i][cc0] = o;
  }
  __syncthreads();
  int col = tid & 31, rgrp = tid >> 5;
  float a2[10];
  #pragma unroll
  for (int i = 0; i < 10; i++) a2[i] = bqkv[rgrp*10 + i];
  for (int k = 0; k < 64; k++){
    float sv = s_lds[k][col];
    #pragma unroll
    for (int i = 0; i < 10; i++) a2[i] += wq_lds[rgrp*10 + i][k]*sv;
  }
  __hip_bfloat16* Vb = reinterpret_cast<__hip_bfloat16*>(wsp + OFF_V);
  int hw = hw0 + col;
  #pragma unroll
  for (int i = 0; i < 10; i++){
    int r = rgrp*10 + i;
    if (r < 8)       wsp[OFF_Q + (size_t)b*18432 + (size_t)r*2304 + hw] = a2[i];
    else if (r < 16) wsp[OFF_K + (size_t)b*18432 + (size_t)(r-8)*2304 + hw] = a2[i];
    else             Vb[(size_t)b*147456 + (size_t)(r-16)*2304 + hw] = __float2bfloat16(a2[i]);
  }
}

// ---------------- K4: flash attention: QK^T -> softmax -> PV -> gamma*pv+s ----------------
// grid (144, 2). 16 m-rows per block. Logits parked in LDS as f16 (stride 2312
// shorts -> A-frag reads land 2-way bank aliased = free), converted in place to
// bf16 P per 256-col chunk, MFMA vs lane-local bf16 V global loads.
__global__ __launch_bounds__(256) void k_attn(float* __restrict__ wsp, const float* __restrict__ gamma){
  int mb = blockIdx.x * 16;
  int b  = blockIdx.y;
  int t = threadIdx.x;
  int w = t >> 6, lane = t & 63;
  int arow = lane & 15, kg = lane >> 4;
  __shared__ float qs[16][8];
  __shared__ __align__(16) unsigned short plds[16][2312];
  __shared__ float redM[4][16], redS[4][16];
  __shared__ float tile[16][68];
  const float* Qp = wsp + OFF_Q + (size_t)b*18432;
  const float* Kp = wsp + OFF_K + (size_t)b*18432;
  if (t < 128) qs[t>>3][t&7] = Qp[(size_t)(t&7)*2304 + mb + (t>>3)];
  __syncthreads();
  // preload this thread's 9 K-columns (72 regs)
  float k8[9][8];
  #pragma unroll
  for (int j = 0; j < 9; j++){
    int n = j*256 + t;
    #pragma unroll
    for (int c = 0; c < 8; c++) k8[j][c] = Kp[(size_t)c*2304 + n];
  }
  float mx[16], ssum[16];
  #pragma unroll
  for (int m = 0; m < 16; m++){
    float q0=qs[m][0], q1=qs[m][1], q2=qs[m][2], q3=qs[m][3];
    float q4=qs[m][4], q5=qs[m][5], q6=qs[m][6], q7=qs[m][7];
    float lmx = -1e30f, ls = 0.f;
    #pragma unroll
    for (int j = 0; j < 9; j++){
      float l = q0*k8[j][0]+q1*k8[j][1]+q2*k8[j][2]+q3*k8[j][3]
              + q4*k8[j][4]+q5*k8[j][5]+q6*k8[j][6]+q7*k8[j][7];
      __half hv = __float2half(l);
      plds[m][j*256 + t] = __half_as_ushort(hv);
      float mo = lmx;
      lmx = fmaxf(lmx, l);
      ls = ls*__expf(mo - lmx) + __expf(l - lmx);
    }
    mx[m] = lmx; ssum[m] = ls;
  }
  #pragma unroll
  for (int m = 0; m < 16; m++){
    float M = mx[m], S = ssum[m];
    #pragma unroll
    for (int off = 32; off; off >>= 1){
      float oM = __shfl_xor(M, off), oS = __shfl_xor(S, off);
      float nM = fmaxf(M, oM);
      S = S*__expf(M - nM) + oS*__expf(oM - nM);
      M = nM;
    }
    if (lane == 0){ redM[w][m] = M; redS[w][m] = S; }
  }
  __syncthreads();
  float Mf[16], invS[16];
  #pragma unroll
  for (int m = 0; m < 16; m++){
    float M0 = redM[0][m], M1 = redM[1][m], M2 = redM[2][m], M3 = redM[3][m];
    float M = fmaxf(fmaxf(M0, M1), fmaxf(M2, M3));
    float S = redS[0][m]*__expf(M0-M) + redS[1][m]*__expf(M1-M)
            + redS[2][m]*__expf(M2-M) + redS[3][m]*__expf(M3-M);
    Mf[m] = M; invS[m] = 1.f/S;
  }
  const short* Vb = (const short*)(wsp + OFF_V) + (size_t)b*147456 + (size_t)(w*16 + arow)*2304;
  f32x4 acc = {0.f, 0.f, 0.f, 0.f};
  for (int j = 0; j < 9; j++){
    int n = j*256 + t;
    #pragma unroll
    for (int m = 0; m < 16; m++){
      float l = __half2float(__ushort_as_half(plds[m][n]));
      float p = __expf(l - Mf[m]) * invS[m];
      __hip_bfloat16 pb = __float2bfloat16(p);
      plds[m][n] = *(unsigned short*)&pb;
    }
    __syncthreads();
    #pragma unroll
    for (int ks = 0; ks < 8; ks++){
      int nb = j*256 + ks*32 + kg*8;
      short8 a  = *(const short8*)&plds[arow][nb];
      short8 bv = *(const short8*)(Vb + nb);
      acc = __builtin_amdgcn_mfma_f32_16x16x32_bf16(a, bv, acc, 0, 0, 0);
    }
  }
  #pragma unroll
  for (int r = 0; r < 4; r++) tile[kg*4 + r][w*16 + arow] = acc[r];
  __syncthreads();
  int c = t >> 2, mq = t & 3;
  float g = gamma[0];
  const float* Sp = wsp + OFF_S + (size_t)b*147456 + (size_t)c*2304 + mb + mq*4;
  float4 s4 = *(const float4*)Sp;
  float4 o;
  o.x = g*tile[mq*4+0][c] + s4.x;
  o.y = g*tile[mq*4+1][c] + s4.y;
  o.z = g*tile[mq*4+2][c] + s4.z;
  o.w = g*tile[mq*4+3][c] + s4.w;
  *(float4*)(wsp + OFF_SA + (size_t)b*147456 + (size_t)c*2304 + mb + mq*4) = o;
}

// ---------------- K8: bilinear upsample gc branches (align_corners=True) ----------------
__global__ __launch_bounds__(256) void k_gcup(float* __restrict__ wsp){
  int px = blockIdx.x*256 + threadIdx.x;   // 0..2303
  int pb = blockIdx.y;                     // t*128 + b*64 + c
  int c = pb & 63, b = (pb >> 6) & 1, t = pb >> 7;
  int oy = px / 48, ox = px - oy*48;
  int ps; const float* g;
  if (t == 0){ ps = 1; g = wsp + OFF_G0 + (size_t)b*64; }
  else if (t == 1){ ps = 3; g = wsp + OFF_G1 + (size_t)b*9*64; }
  else { ps = 5; g = wsp + OFF_G2 + (size_t)b*25*64; }
  float scale = (ps - 1) / 47.f;
  float cy = oy*scale, cx = ox*scale;
  int y0 = (int)cy, x0 = (int)cx;
  float wy = cy - y0, wx = cx - x0;
  int y1 = min(y0+1, ps-1), x1 = min(x0+1, ps-1);
  float a  = g[(y0*ps+x0)*64 + c], bq = g[(y0*ps+x1)*64 + c];
  float cc = g[(y1*ps+x0)*64 + c], d  = g[(y1*ps+x1)*64 + c];
  float v = (a*(1.f-wx) + bq*wx)*(1.f-wy) + (cc*(1.f-wx) + d*wx)*wy;
  wsp[OFF_GC + (((size_t)t*2 + b)*64 + c)*2304 + px] = v;
}

// ---------------- K9: spatial mean of SA ----------------
__global__ __launch_bounds__(256) void k_gap(float* __restrict__ wsp){
  __shared__ float red[4];
  int blk = blockIdx.x; int c = blk & 63, b = blk >> 6;   // 128 blocks
  const float* src = wsp + OFF_SA + ((size_t)b*64 + c)*2304;
  float s = 0.f;
  for (int i = threadIdx.x; i < 2304; i += 256) s += src[i];
  #pragma unroll
  for (int o = 32; o; o >>= 1) s += __shfl_xor(s, o);
  if ((threadIdx.x & 63) == 0) red[threadIdx.x >> 6] = s;
  __syncthreads();
  if (threadIdx.x == 0)
    wsp[OFF_MEAN + (size_t)b*64 + c] = (red[0]+red[1]+red[2]+red[3]) * (1.f/2304.f);
}

// ---------------- K10: SE (gc means analytic from G) ----------------
__global__ __launch_bounds__(256) void k_se(
    const float* __restrict__ w_se1, const float* __restrict__ w_se2,
    const float* __restrict__ w_se3, const float* __restrict__ w_se4,
    float* __restrict__ wsp){
  int b = blockIdx.x; int tid = threadIdx.x;
  int g = tid >> 6, c = tid & 63;
  __shared__ float mean_lds[4][64];
  float mv;
  if (g == 0){
    mv = wsp[OFF_MEAN + (size_t)b*64 + c];
  } else if (g == 3){
    mv = wsp[OFF_G0 + (size_t)b*64 + c];
  } else if (g == 2){
    float w3[3] = {0.f,0.f,0.f};
    for (int o = 0; o < 48; o++){
      float cc = o*(2.f/47.f); int i0 = (int)cc; float f = cc - i0;
      int i1 = min(i0+1, 2);
      w3[i0] += 1.f - f; w3[i1] += f;
    }
    float s = 0.f;
    for (int sy = 0; sy < 3; sy++)
      for (int sx = 0; sx < 3; sx++)
        s += w3[sy]*w3[sx]*wsp[OFF_G1 + ((size_t)b*9 + sy*3 + sx)*64 + c];
    mv = s * (1.f/(48.f*48.f));
  } else {
    float w5[5] = {0.f,0.f,0.f,0.f,0.f};
    for (int o = 0; o < 48; o++){
      float cc = o*(4.f/47.f); int i0 = (int)cc; float f = cc - i0;
      int i1 = min(i0+1, 4);
      w5[i0] += 1.f - f; w5[i1] += f;
    }
    float s = 0.f;
    for (int sy = 0; sy < 5; sy++)
      for (int sx = 0; sx < 5; sx++)
        s += w5[sy]*w5[sx]*wsp[OFF_G2 + ((size_t)b*25 + sy*5 + sx)*64 + c];
    mv = s * (1.f/(48.f*48.f));
  }
  mean_lds[g][c] = mv;
  __syncthreads();
  const float* w = (g == 0) ? w_se1 : (g == 1) ? w_se2 : (g == 2) ? w_se3 : w_se4;
  float acc = 0.f;
  for (int j = 0; j < 64; j++) acc += w[(size_t)c*64 + j]*mean_lds[g][j];
  float sg = 1.f / (1.f + __expf(-acc));
  __shared__ float sh[4][64];
  sh[g][c] = sg;
  __syncthreads();
  float a0 = sh[0][c], a1 = sh[1][c], a2 = sh[2][c], a3 = sh[3][c];
  float mxv = fmaxf(fmaxf(a0, a1), fmaxf(a2, a3));
  float e = __expf(sg - mxv);
  float sum = __expf(a0-mxv) + __expf(a1-mxv) + __expf(a2-mxv) + __expf(a3-mxv);
  wsp[OFF_WGT + ((size_t)b*4 + g)*64 + c] = e / sum;
}

// ---------------- K12: out-head GEMMs, X staged via global_load_lds ----------------
__global__ __launch_bounds__(256) void k_outgemm(
    const float* __restrict__ w0, const float* __restrict__ b0,
    const float* __restrict__ w1, const float* __restrict__ b1,
    const float* __restrict__ w2, const float* __restrict__ b2,
    const float* __restrict__ w3, const float* __restrict__ b3,
    float* __restrict__ wsp){
  __shared__ __align__(16) float wt[64][68];
  __shared__ __align__(16) float xsh[64][64];   // staged activation chunk (16 KB, linear)
  __shared__ float wg[256];
  int cb = blockIdx.x, rb = blockIdx.y;
  int b = cb / 36, hw0 = (cb - b*36)*64;
  const float* wsrc; const float* bsrc; size_t dstoff; int dstC; int row0;
  if (rb < 4){ wsrc = w0 + (size_t)rb*64*256; bsrc = b0 + rb*64; dstoff = OFF_Y0; dstC = 256; row0 = rb*64; }
  else if (rb < 6){ wsrc = w1 + (size_t)(rb-4)*64*256; bsrc = b1 + (rb-4)*64; dstoff = OFF_Y1; dstC = 128; row0 = (rb-4)*64; }
  else if (rb == 6){ wsrc = w2; bsrc = b2; dstoff = OFF_Y2; dstC = 64; row0 = 0; }
  else { wsrc = w3; bsrc = b3; dstoff = OFF_Y3; dstC = 64; row0 = 0; }
  int tid = threadIdx.x;
  int wv_ = tid >> 6, lane = tid & 63;
  wg[tid] = wsp[OFF_WGT + (size_t)b*256 + tid];
  int sr = tid >> 2, sseg = tid & 3;
  int cc0 = (tid & 15)*4, r0 = (tid >> 4)*4;
  float acc[4][4] = {};
  for (int kc = 0; kc < 256; kc += 64){
    __syncthreads();
    {
      int gidx = kc >> 6;
      size_t srcbase = (gidx < 3) ? OFF_GC + ((size_t)(gidx*2 + b))*147456
                                  : OFF_SA + (size_t)b*147456;
      const float* gb = wsp + srcbase + hw0 + (lane & 15)*4;
      int rr = wv_*16 + (lane >> 4);
      #pragma unroll
      for (int i = 0; i < 4; i++)
        GLOAD_LDS(gb + (size_t)(rr + i*4)*2304, &xsh[wv_*16 + i*4][0]);
    }
    #pragma unroll
    for (int i = 0; i < 16; i += 4){
      float4 v = *(const float4*)(wsrc + (size_t)sr*256 + kc + sseg*16 + i);
      int kl = sseg*16 + i;
      wt[kl+0][sr]=v.x*wg[kc+kl+0]; wt[kl+1][sr]=v.y*wg[kc+kl+1];
      wt[kl+2][sr]=v.z*wg[kc+kl+2]; wt[kl+3][sr]=v.w*wg[kc+kl+3];
    }
    __syncthreads();
    #pragma unroll 4
    for (int k = 0; k < 64; k++){
      float4 wv = *(const float4*)&wt[k][r0];
      float4 xv = *(const float4*)&xsh[k][cc0];
      acc[0][0]+=wv.x*xv.x; acc[0][1]+=wv.x*xv.y; acc[0][2]+=wv.x*xv.z; acc[0][3]+=wv.x*xv.w;
      acc[1][0]+=wv.y*xv.x; acc[1][1]+=wv.y*xv.y; acc[1][2]+=wv.y*xv.z; acc[1][3]+=wv.y*xv.w;
      acc[2][0]+=wv.z*xv.x; acc[2][1]+=wv.z*xv.y; acc[2][2]+=wv.z*xv.z; acc[2][3]+=wv.z*xv.w;
      acc[3][0]+=wv.w*xv.x; acc[3][1]+=wv.w*xv.y; acc[3][2]+=wv.w*xv.z; acc[3][3]+=wv.w*xv.w;
    }
  }
  #pragma unroll
  for (int i = 0; i < 4; i++){
    float bi = bsrc[r0+i];
    float4 o;
    o.x = fmaxf(acc[i][0]+bi, 0.f); o.y = fmaxf(acc[i][1]+bi, 0.f);
    o.z = fmaxf(acc[i][2]+bi, 0.f); o.w = fmaxf(acc[i][3]+bi, 0.f);
    *(float4*)(wsp + dstoff + ((size_t)b*dstC + row0 + r0 + i)*2304 + hw0 + cc0) = o;
  }
}

// ---------------- K13: all 4 upsample heads ----------------
template<int SC>
__device__ __forceinline__ void up_one(int idx, const float* __restrict__ src, float* __restrict__ dst){
  constexpr int OW = 48*SC, OH = 48*SC;
  constexpr int WQ = OW/4;
  int q = idx % WQ; int rest = idx / WQ;
  int oy = rest % OH; int pc = rest / OH;
  const float* sp = src + (size_t)pc * 2304;
  float cy = fminf(fmaxf((oy + 0.5f)*(1.0f/SC) - 0.5f, 0.f), 47.f);
  int y0 = (int)cy;
  float wy = cy - y0;
  int y1 = min(y0+1, 47);
  const float* r0 = sp + y0*48; const float* r1 = sp + y1*48;
  float outv[4];
  #pragma unroll
  for (int i = 0; i < 4; i++){
    int ox = q*4 + i;
    float cx = fminf(fmaxf((ox + 0.5f)*(1.0f/SC) - 0.5f, 0.f), 47.f);
    int x0 = (int)cx; float wx = cx - x0; int x1 = min(x0+1, 47);
    float a  = r0[x0]*(1.f-wx) + r0[x1]*wx;
    float bq = r1[x0]*(1.f-wx) + r1[x1]*wx;
    outv[i] = a*(1.f-wy) + bq*wy;
  }
  float4 o; o.x = outv[0]; o.y = outv[1]; o.z = outv[2]; o.w = outv[3];
  *(float4*)(dst + (size_t)pc*OH*OW + (size_t)oy*OW + q*4) = o;
}

__global__ __launch_bounds__(256) void k_upsample_all(const float* __restrict__ wsp, float* __restrict__ out){
  int t = blockIdx.x*256 + threadIdx.x;
  if (t < 1179648)       up_one<2>(t,           wsp + OFF_Y0, out);
  else if (t < 3538944)  up_one<4>(t - 1179648, wsp + OFF_Y1, out + 4718592);
  else if (t < 8257536)  up_one<8>(t - 3538944, wsp + OFF_Y2, out + 14155776);
  else                   up_one<16>(t - 8257536, wsp + OFF_Y3, out + 33030144);
}

// ---------------- launcher ----------------
extern "C" void kernel_launch(void* const* d_in, const int* in_sizes, int n_in,
                              void* d_out, int out_size, void* d_ws, size_t ws_size,
                              hipStream_t stream){
  const float* x     = (const float*)d_in[0];
  const float* w_gc0 = (const float*)d_in[1];
  const float* b_gc0 = (const float*)d_in[2];
  const float* w_gc1 = (const float*)d_in[3];
  const float* b_gc1 = (const float*)d_in[4];
  const float* w_gc2 = (const float*)d_in[5];
  const float* b_gc2 = (const float*)d_in[6];
  const float* w_gc3 = (const float*)d_in[7];
  const float* b_gc3 = (const float*)d_in[8];
  const float* w_q   = (const float*)d_in[9];
  const float* b_q   = (const float*)d_in[10];
  const float* w_k   = (const float*)d_in[11];
  const float* b_k   = (const float*)d_in[12];
  const float* w_v   = (const float*)d_in[13];
  const float* b_v   = (const float*)d_in[14];
  const float* gamma = (const float*)d_in[15];
  const float* w_se1 = (const float*)d_in[16];
  const float* w_se2 = (const float*)d_in[17];
  const float* w_se3 = (const float*)d_in[18];
  const float* w_se4 = (const float*)d_in[19];
  const float* w_out0 = (const float*)d_in[20];
  const float* b_out0 = (const float*)d_in[21];
  const float* w_out1 = (const float*)d_in[22];
  const float* b_out1 = (const float*)d_in[23];
  const float* w_out2 = (const float*)d_in[24];
  const float* b_out2 = (const float*)d_in[25];
  const float* w_out3 = (const float*)d_in[26];
  const float* b_out3 = (const float*)d_in[27];
  float* wsp = (float*)d_ws;
  float* out = (float*)d_out;

  k_pool     <<<1024, 256, 0, stream>>>(x, wsp);
  k_gcconv   <<<70,   256, 0, stream>>>(w_gc0,b_gc0,w_gc1,b_gc1,w_gc2,b_gc2, wsp);
  k_sgemm_qkv<<<144,  256, 0, stream>>>(x, w_gc3, b_gc3, w_q,b_q,w_k,b_k,w_v,b_v, wsp);
  k_attn     <<<dim3(144,2), 256, 0, stream>>>(wsp, gamma);
  k_gcup     <<<dim3(9,384), 256, 0, stream>>>(wsp);
  k_gap      <<<128,  256, 0, stream>>>(wsp);
  k_se       <<<2,    256, 0, stream>>>(w_se1,w_se2,w_se3,w_se4, wsp);
  k_outgemm  <<<dim3(72,8), 256, 0, stream>>>(w_out0,b_out0,w_out1,b_out1,w_out2,b_out2,w_out3,b_out3, wsp);
  k_upsample_all<<<105984, 256, 0, stream>>>(wsp, out);
}